// Round 1
// baseline (10834.437 us; speedup 1.0000x reference)
//
#include <hip/hip_runtime.h>
#include <hip/hip_bf16.h>
#include <math.h>

#define B_  256
#define L_  100
#define H_  384
#define NH_ 12
#define DH_ 32
#define NL_ 6
#define FF_ 1536
#define M_  (B_*L_)   // 25600 rows

// ---------------- embedding: h = (tok[x] + seg[s] + pos[l]) * nonpad ----------------
__global__ void embed_kernel(const int* __restrict__ x, const int* __restrict__ seg,
                             const float* __restrict__ tok, const float* __restrict__ sege,
                             const float* __restrict__ pos, float* __restrict__ out) {
    int idx = blockIdx.x * blockDim.x + threadIdx.x;
    if (idx >= M_ * H_) return;
    int m = idx / H_;
    int f = idx - m * H_;
    int t = x[m];
    int s = seg[m];
    int l = m % L_;
    float v = tok[t * H_ + f] + sege[s * H_ + f] + pos[l * H_ + f];
    out[idx] = (t != 0) ? v : 0.0f;
}

// ---------------- fp32 tiled GEMM: C[M,N] = A[M,K] @ W[K,N] + bias[N] (+gelu) -------
// M%64==0, N%64==0, K%16==0 for all shapes used here.
__global__ __launch_bounds__(256) void gemm_kernel(const float* __restrict__ A,
        const float* __restrict__ W, const float* __restrict__ bias,
        float* __restrict__ C, int M, int N, int K, int act) {
    __shared__ float As[16][65];   // padded: transposed A tile
    __shared__ float Ws[16][64];
    int tid = threadIdx.x;
    int tx = tid & 15, ty = tid >> 4;
    int bm = blockIdx.y * 64, bn = blockIdx.x * 64;
    float acc[4][4] = {};

    int am = tid >> 2;          // 0..63  (A row within tile)
    int ak = (tid & 3) * 4;     // 0,4,8,12 (A col4 within k-tile)
    int wk = tid >> 4;          // 0..15  (W row within k-tile)
    int wn = (tid & 15) * 4;    // W col4 within tile
    const float* Aptr = A + (size_t)(bm + am) * K + ak;
    const float* Wptr = W + (size_t)wk * N + bn + wn;

    for (int k0 = 0; k0 < K; k0 += 16) {
        float4 av = *(const float4*)(Aptr + k0);
        float4 wv = *(const float4*)(Wptr + (size_t)k0 * N);
        As[ak + 0][am] = av.x;
        As[ak + 1][am] = av.y;
        As[ak + 2][am] = av.z;
        As[ak + 3][am] = av.w;
        *(float4*)&Ws[wk][wn] = wv;
        __syncthreads();
        #pragma unroll
        for (int k = 0; k < 16; ++k) {
            float a0[4], b0[4];
            #pragma unroll
            for (int i = 0; i < 4; ++i) a0[i] = As[k][ty * 4 + i];
            #pragma unroll
            for (int j = 0; j < 4; ++j) b0[j] = Ws[k][tx * 4 + j];
            #pragma unroll
            for (int i = 0; i < 4; ++i)
                #pragma unroll
                for (int j = 0; j < 4; ++j)
                    acc[i][j] += a0[i] * b0[j];
        }
        __syncthreads();
    }

    int col0 = bn + tx * 4;
    float4 bv = *(const float4*)&bias[col0];
    #pragma unroll
    for (int i = 0; i < 4; ++i) {
        int row = bm + ty * 4 + i;
        float4 o;
        o.x = acc[i][0] + bv.x;
        o.y = acc[i][1] + bv.y;
        o.z = acc[i][2] + bv.z;
        o.w = acc[i][3] + bv.w;
        if (act == 1) {
            const float c0 = 0.7978845608f;  // sqrt(2/pi)
            float* p = &o.x;
            #pragma unroll
            for (int j = 0; j < 4; ++j) {
                float v = p[j];
                float t = c0 * (v + 0.044715f * v * v * v);
                p[j] = v * 0.5f * (1.0f + tanhf(t));
            }
        }
        *(float4*)&C[(size_t)row * N + col0] = o;
    }
}

// ---------------- fused attention per (b, head): QK^T -> mask -> softmax -> PV ------
// Interleaved split: q[nh,b,l,d] = qlin[b,l,d*NH+nh]; output concat a[b,l,nh*DH+d].
__global__ __launch_bounds__(128) void attn_kernel(const float* __restrict__ q,
        const float* __restrict__ k, const float* __restrict__ v,
        const int* __restrict__ x, float* __restrict__ a) {
    __shared__ float ks[L_][DH_ + 1];
    __shared__ float vs[L_][DH_];
    __shared__ float qs[50][DH_];
    __shared__ float es[50][L_ + 1];
    __shared__ int xb[L_];
    int tid = threadIdx.x;
    int b = blockIdx.x / NH_;
    int nh = blockIdx.x % NH_;
    const float* qb = q + (size_t)b * L_ * H_;
    const float* kb = k + (size_t)b * L_ * H_;
    const float* vb = v + (size_t)b * L_ * H_;

    for (int i = tid; i < L_ * DH_; i += 128) {
        int l = i >> 5, d = i & 31;
        ks[l][d] = kb[l * H_ + d * NH_ + nh];
        vs[l][d] = vb[l * H_ + d * NH_ + nh];
    }
    for (int i = tid; i < L_; i += 128) xb[i] = x[b * L_ + i];
    const float scale = 1.0f / sqrtf((float)H_);   // quirky: 1/sqrt(hidden_dim)

    for (int half = 0; half < 2; ++half) {
        __syncthreads();
        for (int i = tid; i < 50 * DH_; i += 128) {
            int l = i >> 5, d = i & 31;
            qs[l][d] = qb[(size_t)(half * 50 + l) * H_ + d * NH_ + nh];
        }
        __syncthreads();
        for (int i = tid; i < 50 * L_; i += 128) {
            int l = i / L_, m = i - l * L_;
            float s = 0.0f;
            #pragma unroll
            for (int d = 0; d < DH_; ++d) s += qs[l][d] * ks[m][d];
            es[l][m] = (xb[m] == 0) ? -1e10f : s * scale;
        }
        __syncthreads();
        if (tid < 50) {
            float mx = -INFINITY;
            for (int m2 = 0; m2 < L_; ++m2) mx = fmaxf(mx, es[tid][m2]);
            float sum = 0.0f;
            for (int m2 = 0; m2 < L_; ++m2) {
                float t = expf(es[tid][m2] - mx);
                es[tid][m2] = t;
                sum += t;
            }
            float inv = 1.0f / sum;
            for (int m2 = 0; m2 < L_; ++m2) es[tid][m2] *= inv;
        }
        __syncthreads();
        for (int i = tid; i < 50 * DH_; i += 128) {
            int l = i >> 5, d = i & 31;
            float s = 0.0f;
            for (int m2 = 0; m2 < L_; ++m2) s += es[l][m2] * vs[m2][d];
            a[(size_t)(b * L_ + half * 50 + l) * H_ + nh * DH_ + d] = s;
        }
        __syncthreads();
    }
}

// ---------------- fused residual + LayerNorm (scalar g,b; ddof=1) * nonpad ---------
// Y = (g*((X+R - mu)/sqrt(var+1e-8)) + b) * nonpad ; optionally acc += Y
template <bool ADD_ACC>
__global__ __launch_bounds__(128) void ln_kernel(const float* __restrict__ X,
        const float* __restrict__ R, const int* __restrict__ x,
        const float* __restrict__ gp, const float* __restrict__ bp, int layer,
        float* __restrict__ Y, float* __restrict__ acc) {
    int row = blockIdx.x;
    int tid = threadIdx.x;
    size_t base = (size_t)row * H_;
    float v0 = X[base + tid]       + R[base + tid];
    float v1 = X[base + tid + 128] + R[base + tid + 128];
    float v2 = X[base + tid + 256] + R[base + tid + 256];

    __shared__ float red[2];
    float s = v0 + v1 + v2;
    #pragma unroll
    for (int off = 32; off > 0; off >>= 1) s += __shfl_down(s, off);
    if ((tid & 63) == 0) red[tid >> 6] = s;
    __syncthreads();
    float mu = (red[0] + red[1]) * (1.0f / 384.0f);
    __syncthreads();

    float d0 = v0 - mu, d1 = v1 - mu, d2 = v2 - mu;
    float qq = d0 * d0 + d1 * d1 + d2 * d2;
    #pragma unroll
    for (int off = 32; off > 0; off >>= 1) qq += __shfl_down(qq, off);
    if ((tid & 63) == 0) red[tid >> 6] = qq;
    __syncthreads();
    float var = (red[0] + red[1]) * (1.0f / 383.0f);   // unbiased (ddof=1)
    float rstd = rsqrtf(var + 1e-8f);

    float g = gp[layer], bb = bp[layer];
    float np_ = (x[row] != 0) ? 1.0f : 0.0f;
    float y0 = (g * (d0 * rstd) + bb) * np_;
    float y1 = (g * (d1 * rstd) + bb) * np_;
    float y2 = (g * (d2 * rstd) + bb) * np_;
    Y[base + tid]       = y0;
    Y[base + tid + 128] = y1;
    Y[base + tid + 256] = y2;
    if (ADD_ACC) {
        acc[base + tid]       += y0;
        acc[base + tid + 128] += y1;
        acc[base + tid + 256] += y2;
    }
}

extern "C" void kernel_launch(void* const* d_in, const int* in_sizes, int n_in,
                              void* d_out, int out_size, void* d_ws, size_t ws_size,
                              hipStream_t stream) {
    const int*   x    = (const int*)d_in[0];
    const int*   seg  = (const int*)d_in[1];
    const float* tok  = (const float*)d_in[2];
    const float* sege = (const float*)d_in[3];
    const float* pos  = (const float*)d_in[4];
    const float* Wq   = (const float*)d_in[5];
    const float* bq   = (const float*)d_in[6];
    const float* Wk   = (const float*)d_in[7];
    const float* bk   = (const float*)d_in[8];
    const float* Wv   = (const float*)d_in[9];
    const float* bv   = (const float*)d_in[10];
    const float* Wo   = (const float*)d_in[11];
    const float* bo   = (const float*)d_in[12];
    const float* g1   = (const float*)d_in[13];
    const float* be1  = (const float*)d_in[14];
    const float* W1   = (const float*)d_in[15];
    const float* b1   = (const float*)d_in[16];
    const float* W2   = (const float*)d_in[17];
    const float* b2   = (const float*)d_in[18];
    const float* g2   = (const float*)d_in[19];
    const float* be2  = (const float*)d_in[20];

    float* ws = (float*)d_ws;
    const size_t S = (size_t)M_ * H_;
    float* acc = ws;             // persistent cumulative skip
    float* bQ  = ws + 1 * S;     // q  (later reused as part of f)
    float* bK  = ws + 2 * S;     // k
    float* bV  = ws + 3 * S;     // v
    float* bA  = ws + 4 * S;     // concat'd heads
    float* bE  = ws + 5 * S;     // Wo-GEMM tmp, then attn (post-LN1)
    float* f   = ws + 1 * S;     // FFN hidden: spans q,k,v,a regions (4*S floats)
    float* out = (float*)d_out;

    {
        int total = M_ * H_;
        embed_kernel<<<dim3((total + 255) / 256), dim3(256), 0, stream>>>(x, seg, tok, sege, pos, acc);
    }

    dim3 gH(H_ / 64, M_ / 64);
    dim3 gF(FF_ / 64, M_ / 64);
    for (int l = 0; l < NL_; ++l) {
        const float* wq = Wq + (size_t)l * H_ * H_;
        const float* wk = Wk + (size_t)l * H_ * H_;
        const float* wv = Wv + (size_t)l * H_ * H_;
        const float* wo = Wo + (size_t)l * H_ * H_;
        const float* w1 = W1 + (size_t)l * H_ * FF_;
        const float* w2 = W2 + (size_t)l * FF_ * H_;
        const float* bql = bq + (size_t)l * H_;
        const float* bkl = bk + (size_t)l * H_;
        const float* bvl = bv + (size_t)l * H_;
        const float* bol = bo + (size_t)l * H_;
        const float* b1l = b1 + (size_t)l * FF_;
        const float* b2l = b2 + (size_t)l * H_;

        // QKV projections
        gemm_kernel<<<gH, 256, 0, stream>>>(acc, wq, bql, bQ, M_, H_, H_, 0);
        gemm_kernel<<<gH, 256, 0, stream>>>(acc, wk, bkl, bK, M_, H_, H_, 0);
        gemm_kernel<<<gH, 256, 0, stream>>>(acc, wv, bvl, bV, M_, H_, H_, 0);
        // fused attention (interleaved-head gather, 1/sqrt(H) scale, key pad mask)
        attn_kernel<<<dim3(B_ * NH_), dim3(128), 0, stream>>>(bQ, bK, bV, x, bA);
        // output projection -> tmp(bE); LN1(tmp + acc) -> attn(bE in-place)
        gemm_kernel<<<gH, 256, 0, stream>>>(bA, wo, bol, bE, M_, H_, H_, 0);
        ln_kernel<false><<<dim3(M_), dim3(128), 0, stream>>>(bE, acc, x, g1, be1, l, bE, nullptr);
        // FFN
        gemm_kernel<<<gF, 256, 0, stream>>>(bE, w1, b1l, f, M_, FF_, H_, 1);
        gemm_kernel<<<gH, 256, 0, stream>>>(f, w2, b2l, out, M_, H_, FF_, 0);
        // LN2(ffn_out + attn) -> out (d_out), and acc += out
        ln_kernel<true><<<dim3(M_), dim3(128), 0, stream>>>(out, bE, x, g2, be2, l, out, acc);
    }
}

// Round 5
// 7816.384 us; speedup vs baseline: 1.3861x; 1.3861x over previous
//
#include <hip/hip_runtime.h>
#include <hip/hip_bf16.h>
#include <math.h>

#define B_  256
#define L_  100
#define H_  384
#define NH_ 12
#define DH_ 32
#define NL_ 6
#define FF_ 1536
#define M_  (B_*L_)   // 25600 rows
#define QKVN 1152     // 3*H
#define MCH 6400      // rows per chunk (M/4)
#define BCH 64        // batches per chunk

typedef __attribute__((ext_vector_type(8))) short short8;
typedef __attribute__((ext_vector_type(4))) float f32x4;

#define GLOBAL_AS __attribute__((address_space(1)))
#define LDS_AS    __attribute__((address_space(3)))

__device__ __forceinline__ void gload_lds16(const void* g, void* l) {
    __builtin_amdgcn_global_load_lds((const GLOBAL_AS void*)g, (LDS_AS void*)l, 16, 0, 0);
}

__device__ __forceinline__ void split2(float v, __hip_bfloat16& hi, __hip_bfloat16& lo) {
    hi = __float2bfloat16(v);
    lo = __float2bfloat16(v - __bfloat162float(hi));
}

// ---------------- embedding: acc2 = split(tok[x] + seg[s] + pos[l]) * nonpad -------
__global__ void embed_kernel(const int* __restrict__ x, const int* __restrict__ seg,
                             const float* __restrict__ tok, const float* __restrict__ sege,
                             const float* __restrict__ pos,
                             __hip_bfloat16* __restrict__ acc2) {
    int idx = blockIdx.x * blockDim.x + threadIdx.x;
    if (idx >= M_ * H_) return;
    int m = idx / H_;
    int f = idx - m * H_;
    int t = x[m];
    int s = seg[m];
    int l = m % L_;
    float v = tok[t * H_ + f] + sege[s * H_ + f] + pos[l * H_ + f];
    v = (t != 0) ? v : 0.0f;
    __hip_bfloat16 h, lo;
    split2(v, h, lo);
    acc2[(size_t)m * (2 * H_) + f]      = h;
    acc2[(size_t)m * (2 * H_) + H_ + f] = lo;
}

// ------- weight transpose + f32->bf16x2: in [K][N] -> out [N][2K] (hi | lo) --------
__global__ void transpose_w_kernel(const float* __restrict__ in, __hip_bfloat16* __restrict__ out,
                                   int K, int N, size_t in_lstride, size_t out_lstride) {
    __shared__ float tile[32][33];
    const float* inp = in + (size_t)blockIdx.z * in_lstride;
    __hip_bfloat16* outp = out + (size_t)blockIdx.z * out_lstride;
    int k0 = blockIdx.y * 32, n0 = blockIdx.x * 32;
    int tx = threadIdx.x, ty = threadIdx.y;
    #pragma unroll
    for (int i = ty; i < 32; i += 8)
        tile[i][tx] = inp[(size_t)(k0 + i) * N + (n0 + tx)];
    __syncthreads();
    #pragma unroll
    for (int i = ty; i < 32; i += 8) {
        float v = tile[tx][i];
        __hip_bfloat16 h, lo;
        split2(v, h, lo);
        outp[(size_t)(n0 + i) * (2 * K) + (k0 + tx)]     = h;
        outp[(size_t)(n0 + i) * (2 * K) + K + (k0 + tx)] = lo;
    }
}

__global__ void bias_concat_kernel(const float* __restrict__ bq, const float* __restrict__ bk,
                                   const float* __restrict__ bv, float* __restrict__ out) {
    int i = blockIdx.x * 256 + threadIdx.x;
    if (i >= NL_ * QKVN) return;
    int l = i / QKVN, j = i - l * QKVN;
    float v = (j < 384) ? bq[l * 384 + j] : (j < 768 ? bk[l * 384 + j - 384] : bv[l * 384 + j - 768]);
    out[i] = v;
}

// ------ 3-term split-precision MFMA GEMM: C = A_hi@W_hi + A_hi@W_lo + A_lo@W_hi ----
// A2 [M][2K] = (hi|lo), Wt2 [N][2K] = (hi|lo). Logical K-loop runs 3K steps with
// per-segment offset remap: A segments [hi,hi,lo], W segments [hi,lo,hi]. Dropped
// term lo@lo ~ 2^-18 relative -> fp32-grade product. 128x128 tile, BK=32, 4 waves.
__global__ __launch_bounds__(256) void gemm_bf16_kernel(
        const __hip_bfloat16* __restrict__ A2,   // [M][2K]
        const __hip_bfloat16* __restrict__ Wt2,  // [N][2K]
        const float* __restrict__ bias,          // [N]
        float* __restrict__ Cf,                  // optional f32 out [M][N]
        __hip_bfloat16* __restrict__ C2,         // optional bf16x2 out [M][2N]
        int M, int N, int K, int act) {
    __shared__ __hip_bfloat16 As[128 * 32];
    __shared__ __hip_bfloat16 Bs[128 * 32];
    int t = threadIdx.x;
    int lane = t & 63, wv = t >> 6;
    int wm = wv >> 1, wn = wv & 1;
    int bm = blockIdx.y * 128, bn = blockIdx.x * 128;

    const int Kst  = 2 * K;   // storage stride
    const int Kend = 3 * K;   // logical loop length

    f32x4 acc[4][4] = {};

    const __hip_bfloat16* a_src = A2 + (size_t)(bm + (t >> 2)) * Kst + (t & 3) * 8;
    const __hip_bfloat16* b_src = Wt2 + (size_t)(bn + (t >> 2)) * Kst + (t & 3) * 8;
    __hip_bfloat16* aDst0 = As + wv * 512;
    __hip_bfloat16* aDst1 = As + 2048 + wv * 512;
    __hip_bfloat16* bDst0 = Bs + wv * 512;
    __hip_bfloat16* bDst1 = Bs + 2048 + wv * 512;

    int aOff = (wm * 64 + (lane & 15)) * 32 + (lane >> 4) * 8;
    int bOff = (wn * 64 + (lane & 15)) * 32 + (lane >> 4) * 8;

    for (int k0 = 0; k0 < Kend; k0 += 32) {
        int ak = (k0 < K)     ? k0 : k0 - K;      // A: [hi, hi, lo]
        int wk = (k0 < 2 * K) ? k0 : k0 - 2 * K;  // W: [hi, lo, hi]
        gload_lds16(a_src + ak, aDst0);
        gload_lds16(a_src + (size_t)64 * Kst + ak, aDst1);
        gload_lds16(b_src + wk, bDst0);
        gload_lds16(b_src + (size_t)64 * Kst + wk, bDst1);
        __syncthreads();
        short8 af[4], bf[4];
        #pragma unroll
        for (int m = 0; m < 4; ++m)
            af[m] = *(const short8*)(As + aOff + m * 16 * 32);
        #pragma unroll
        for (int n = 0; n < 4; ++n)
            bf[n] = *(const short8*)(Bs + bOff + n * 16 * 32);
        #pragma unroll
        for (int m = 0; m < 4; ++m)
            #pragma unroll
            for (int n = 0; n < 4; ++n)
                acc[m][n] = __builtin_amdgcn_mfma_f32_16x16x32_bf16(af[m], bf[n], acc[m][n], 0, 0, 0);
        __syncthreads();
    }

    int colBase = bn + wn * 64 + (lane & 15);
    int rowBase = bm + wm * 64 + (lane >> 4) * 4;
    const float c0 = 0.7978845608f;  // sqrt(2/pi)
    #pragma unroll
    for (int n = 0; n < 4; ++n) {
        int c = colBase + n * 16;
        float bvv = bias[c];
        #pragma unroll
        for (int m = 0; m < 4; ++m) {
            int r0 = rowBase + m * 16;
            #pragma unroll
            for (int r = 0; r < 4; ++r) {
                float v = acc[m][n][r] + bvv;
                if (act == 1) {
                    float u = c0 * (v + 0.044715f * v * v * v);
                    v = v * 0.5f * (1.0f + tanhf(u));
                }
                size_t row = (size_t)(r0 + r);
                if (Cf) Cf[row * N + c] = v;
                if (C2) {
                    __hip_bfloat16 h, lo;
                    split2(v, h, lo);
                    C2[row * (2 * N) + c]     = h;
                    C2[row * (2 * N) + N + c] = lo;
                }
            }
        }
    }
}

// ---------------- fused attention per (b, head): QK^T -> mask -> softmax -> PV ------
// qkvF: [rows][1152] f32 (chunk-local), interleaved split q[d]=qkv[d*12+nh].
// output concat a2[row, nh*32+d] as bf16x2 (hi | lo at +384), chunk-local pointers.
__global__ __launch_bounds__(128) void attn_kernel(const float* __restrict__ qkvF,
        const int* __restrict__ x, __hip_bfloat16* __restrict__ a2) {
    __shared__ float ks[L_][DH_ + 1];
    __shared__ float vs[L_][DH_];
    __shared__ float qs[50][DH_];
    __shared__ float es[50][L_ + 1];
    __shared__ int xb[L_];
    int tid = threadIdx.x;
    int b = blockIdx.x / NH_;
    int nh = blockIdx.x % NH_;
    const float* qb = qkvF + (size_t)b * L_ * QKVN;

    for (int i = tid; i < L_ * DH_; i += 128) {
        int l = i >> 5, d = i & 31;
        ks[l][d] = qb[l * QKVN + 384 + d * NH_ + nh];
        vs[l][d] = qb[l * QKVN + 768 + d * NH_ + nh];
    }
    for (int i = tid; i < L_; i += 128) xb[i] = x[b * L_ + i];
    const float scale = 1.0f / sqrtf((float)H_);   // quirky: 1/sqrt(hidden_dim)

    for (int half = 0; half < 2; ++half) {
        __syncthreads();
        for (int i = tid; i < 50 * DH_; i += 128) {
            int l = i >> 5, d = i & 31;
            qs[l][d] = qb[(size_t)(half * 50 + l) * QKVN + d * NH_ + nh];
        }
        __syncthreads();
        for (int i = tid; i < 50 * L_; i += 128) {
            int l = i / L_, m = i - l * L_;
            float s = 0.0f;
            #pragma unroll
            for (int d = 0; d < DH_; ++d) s += qs[l][d] * ks[m][d];
            es[l][m] = (xb[m] == 0) ? -1e10f : s * scale;
        }
        __syncthreads();
        if (tid < 50) {
            float mx = -INFINITY;
            for (int m2 = 0; m2 < L_; ++m2) mx = fmaxf(mx, es[tid][m2]);
            float sum = 0.0f;
            for (int m2 = 0; m2 < L_; ++m2) {
                float tt = expf(es[tid][m2] - mx);
                es[tid][m2] = tt;
                sum += tt;
            }
            float inv = 1.0f / sum;
            for (int m2 = 0; m2 < L_; ++m2) es[tid][m2] *= inv;
        }
        __syncthreads();
        for (int i = tid; i < 50 * DH_; i += 128) {
            int l = i >> 5, d = i & 31;
            float s = 0.0f;
            for (int m2 = 0; m2 < L_; ++m2) s += es[l][m2] * vs[m2][d];
            size_t row = (size_t)(b * L_ + half * 50 + l);
            __hip_bfloat16 h, lo;
            split2(s, h, lo);
            a2[row * (2 * H_) + nh * DH_ + d]      = h;
            a2[row * (2 * H_) + H_ + nh * DH_ + d] = lo;
        }
        __syncthreads();
    }
}

// ---------------- fused residual + LayerNorm (scalar g,b; ddof=1) * nonpad ---------
// X = Xf (f32), residual R2 (bf16x2 recon).
// MODE 0 (LN1): Y -> Y2 (bf16x2)
// MODE 1 (LN2): Y -> Yf (f32) ; acc2 = split(recon(acc2) + Y)
template <int MODE>
__global__ __launch_bounds__(128) void ln_kernel(
        const float* __restrict__ Xf,
        const __hip_bfloat16* __restrict__ R2,
        const int* __restrict__ x,
        const float* __restrict__ gp, const float* __restrict__ bp, int layer,
        float* __restrict__ Yf,
        __hip_bfloat16* __restrict__ Y2,
        __hip_bfloat16* __restrict__ acc2) {
    int row = blockIdx.x;
    int tid = threadIdx.x;
    size_t b1 = (size_t)row * H_;
    size_t b2 = (size_t)row * (2 * H_);

    float v[3];
    #pragma unroll
    for (int j = 0; j < 3; ++j) {
        int f = tid + j * 128;
        float r = __bfloat162float(R2[b2 + f]) + __bfloat162float(R2[b2 + H_ + f]);
        v[j] = Xf[b1 + f] + r;
    }

    __shared__ float red[2];
    float s = v[0] + v[1] + v[2];
    #pragma unroll
    for (int off = 32; off > 0; off >>= 1) s += __shfl_down(s, off);
    if ((tid & 63) == 0) red[tid >> 6] = s;
    __syncthreads();
    float mu = (red[0] + red[1]) * (1.0f / 384.0f);
    __syncthreads();

    float d[3];
    float qq = 0.0f;
    #pragma unroll
    for (int j = 0; j < 3; ++j) { d[j] = v[j] - mu; qq += d[j] * d[j]; }
    #pragma unroll
    for (int off = 32; off > 0; off >>= 1) qq += __shfl_down(qq, off);
    if ((tid & 63) == 0) red[tid >> 6] = qq;
    __syncthreads();
    float var = (red[0] + red[1]) * (1.0f / 383.0f);   // unbiased (ddof=1)
    float rstd = rsqrtf(var + 1e-8f);

    float g = gp[layer], bb = bp[layer];
    float np_ = (x[row] != 0) ? 1.0f : 0.0f;
    #pragma unroll
    for (int j = 0; j < 3; ++j) {
        int f = tid + j * 128;
        float y = (g * (d[j] * rstd) + bb) * np_;
        if (MODE == 0) {
            __hip_bfloat16 h, lo;
            split2(y, h, lo);
            Y2[b2 + f]      = h;
            Y2[b2 + H_ + f] = lo;
        } else {
            Yf[b1 + f] = y;
            float a = __bfloat162float(acc2[b2 + f]) + __bfloat162float(acc2[b2 + H_ + f]) + y;
            __hip_bfloat16 h, lo;
            split2(a, h, lo);
            acc2[b2 + f]      = h;
            acc2[b2 + H_ + f] = lo;
        }
    }
}

extern "C" void kernel_launch(void* const* d_in, const int* in_sizes, int n_in,
                              void* d_out, int out_size, void* d_ws, size_t ws_size,
                              hipStream_t stream) {
    const int*   x    = (const int*)d_in[0];
    const int*   seg  = (const int*)d_in[1];
    const float* tok  = (const float*)d_in[2];
    const float* sege = (const float*)d_in[3];
    const float* pos  = (const float*)d_in[4];
    const float* Wq   = (const float*)d_in[5];
    const float* bq   = (const float*)d_in[6];
    const float* Wk   = (const float*)d_in[7];
    const float* bk   = (const float*)d_in[8];
    const float* Wv   = (const float*)d_in[9];
    const float* bv   = (const float*)d_in[10];
    const float* Wo   = (const float*)d_in[11];
    const float* bo   = (const float*)d_in[12];
    const float* g1   = (const float*)d_in[13];
    const float* be1  = (const float*)d_in[14];
    const float* W1   = (const float*)d_in[15];
    const float* b1   = (const float*)d_in[16];
    const float* W2   = (const float*)d_in[17];
    const float* b2   = (const float*)d_in[18];
    const float* g2   = (const float*)d_in[19];
    const float* be2  = (const float*)d_in[20];

    // per-layer transposed bf16x2 weight layout (elements)
    const size_t LW      = 3538944;
    const size_t OFF_QKV = 0;              // [1152][768]
    const size_t OFF_WO  = 884736;         // [384][768]
    const size_t OFF_W1  = 1179648;        // [1536][768]
    const size_t OFF_W2  = 2359296;        // [384][3072]

    // ---- workspace plan (~191 MiB total; identical to R3 which ran) ----
    char* p = (char*)d_ws;
    __hip_bfloat16* wT2  = (__hip_bfloat16*)p; p += (size_t)NL_ * LW * 2;        // 42.5 MB
    __hip_bfloat16* acc2 = (__hip_bfloat16*)p; p += (size_t)M_ * 2 * H_ * 2;     // 39.3 MB
    __hip_bfloat16* bE2  = (__hip_bfloat16*)p; p += (size_t)M_ * 2 * H_ * 2;     // 39.3 MB
    float* qkvb          = (float*)p;          p += (size_t)NL_ * QKVN * 4;      // 27 KB
    char* bufA           = p;                  p += (size_t)M_ * H_ * 4;         // 39.3 MB
    char* bufB           = p;                  p += (size_t)M_ * 2 * H_ * 2;     // 39.3 MB
    // bufA: qkvF quarter [MCH][1152] f32 (29.5 MB) / wo_f32 [M][384] f32 (39.3 MB)
    // bufB: bA2 [M][768] bf16x2 (39.3 MB) / f2 quarter [MCH][3072] bf16 (39.3 MB)
    float*          qkvF = (float*)bufA;
    float*          woF  = (float*)bufA;
    __hip_bfloat16* bA2  = (__hip_bfloat16*)bufB;
    __hip_bfloat16* f2   = (__hip_bfloat16*)bufB;
    float* out = (float*)d_out;

    // ---- weight prep ----
    {
        dim3 tb(32, 8);
        transpose_w_kernel<<<dim3(H_/32, H_/32, NL_), tb, 0, stream>>>(Wq, wT2 + OFF_QKV,           H_,  H_,  (size_t)H_*H_,  LW);
        transpose_w_kernel<<<dim3(H_/32, H_/32, NL_), tb, 0, stream>>>(Wk, wT2 + OFF_QKV + 384*768, H_,  H_,  (size_t)H_*H_,  LW);
        transpose_w_kernel<<<dim3(H_/32, H_/32, NL_), tb, 0, stream>>>(Wv, wT2 + OFF_QKV + 768*768, H_,  H_,  (size_t)H_*H_,  LW);
        transpose_w_kernel<<<dim3(H_/32, H_/32, NL_), tb, 0, stream>>>(Wo, wT2 + OFF_WO,            H_,  H_,  (size_t)H_*H_,  LW);
        transpose_w_kernel<<<dim3(FF_/32, H_/32, NL_), tb, 0, stream>>>(W1, wT2 + OFF_W1,           H_,  FF_, (size_t)H_*FF_, LW);
        transpose_w_kernel<<<dim3(H_/32, FF_/32, NL_), tb, 0, stream>>>(W2, wT2 + OFF_W2,           FF_, H_,  (size_t)FF_*H_, LW);
        bias_concat_kernel<<<dim3((NL_*QKVN + 255)/256), dim3(256), 0, stream>>>(bq, bk, bv, qkvb);
    }

    // ---- embedding -> acc2 ----
    embed_kernel<<<dim3((M_*H_ + 255)/256), dim3(256), 0, stream>>>(x, seg, tok, sege, pos, acc2);

    dim3 blk(256);
    for (int l = 0; l < NL_; ++l) {
        const __hip_bfloat16* wqkvT = wT2 + (size_t)l * LW + OFF_QKV;
        const __hip_bfloat16* woT   = wT2 + (size_t)l * LW + OFF_WO;
        const __hip_bfloat16* w1T   = wT2 + (size_t)l * LW + OFF_W1;
        const __hip_bfloat16* w2T   = wT2 + (size_t)l * LW + OFF_W2;
        const float* bol = bo + (size_t)l * H_;
        const float* b1l = b1 + (size_t)l * FF_;
        const float* b2l = b2 + (size_t)l * H_;

        // QKV + attention, in 4 row-quarters (qkvF quarter buffer reused)
        for (int q = 0; q < 4; ++q) {
            gemm_bf16_kernel<<<dim3(QKVN/128, MCH/128), blk, 0, stream>>>(
                acc2 + (size_t)q * MCH * 2 * H_, wqkvT, qkvb + (size_t)l * QKVN,
                qkvF, nullptr, MCH, QKVN, H_, 0);
            attn_kernel<<<dim3(BCH * NH_), dim3(128), 0, stream>>>(
                qkvF, x + (size_t)q * BCH * L_, bA2 + (size_t)q * MCH * 2 * H_);
        }
        // Wo: [M,768] @ [384,768]^T (3-term) -> woF (f32, bufA; bA2 in bufB stays live)
        gemm_bf16_kernel<<<dim3(H_/128, M_/128), blk, 0, stream>>>(
            bA2, woT, bol, woF, nullptr, M_, H_, H_, 0);
        // LN1(woF + acc2) -> bE2 (bf16x2)
        ln_kernel<0><<<dim3(M_), dim3(128), 0, stream>>>(
            woF, acc2, x, g1, be1, l, nullptr, bE2, nullptr);
        // FFN in 4 row-quarters: W1(+gelu) -> f2 quarter (bufB, bA2 dead) ; W2 -> out rows
        for (int q = 0; q < 4; ++q) {
            gemm_bf16_kernel<<<dim3(FF_/128, MCH/128), blk, 0, stream>>>(
                bE2 + (size_t)q * MCH * 2 * H_, w1T, b1l, nullptr, f2, MCH, FF_, H_, 1);
            gemm_bf16_kernel<<<dim3(H_/128, MCH/128), blk, 0, stream>>>(
                f2, w2T, b2l, out + (size_t)q * MCH * H_, nullptr, MCH, H_, FF_, 0);
        }
        // LN2(out + bE2) -> out (f32, in-place) ; acc2 = split(recon(acc2) + out)
        ln_kernel<1><<<dim3(M_), dim3(128), 0, stream>>>(
            out, bE2, x, g2, be2, l, out, nullptr, acc2);
    }
}

// Round 6
// 5320.470 us; speedup vs baseline: 2.0364x; 1.4691x over previous
//
#include <hip/hip_runtime.h>
#include <hip/hip_bf16.h>
#include <math.h>

#define B_  256
#define L_  100
#define H_  384
#define NH_ 12
#define DH_ 32
#define NL_ 6
#define FF_ 1536
#define M_  (B_*L_)   // 25600 rows
#define QKVN 1152     // 3*H

typedef __attribute__((ext_vector_type(8))) short short8;
typedef __attribute__((ext_vector_type(4))) float f32x4;

#define GLOBAL_AS __attribute__((address_space(1)))
#define LDS_AS    __attribute__((address_space(3)))

__device__ __forceinline__ void gload_lds16(const void* g, void* l) {
    __builtin_amdgcn_global_load_lds((const GLOBAL_AS void*)g, (LDS_AS void*)l, 16, 0, 0);
}

__device__ __forceinline__ void split2(float v, __hip_bfloat16& hi, __hip_bfloat16& lo) {
    hi = __float2bfloat16(v);
    lo = __float2bfloat16(v - __bfloat162float(hi));
}

// ---------------- embedding: acc2 = split(tok[x] + seg[s] + pos[l]) * nonpad -------
__global__ void embed_kernel(const int* __restrict__ x, const int* __restrict__ seg,
                             const float* __restrict__ tok, const float* __restrict__ sege,
                             const float* __restrict__ pos,
                             __hip_bfloat16* __restrict__ acc2) {
    int idx = blockIdx.x * blockDim.x + threadIdx.x;
    if (idx >= M_ * H_) return;
    int m = idx / H_;
    int f = idx - m * H_;
    int t = x[m];
    int s = seg[m];
    int l = m % L_;
    float v = tok[t * H_ + f] + sege[s * H_ + f] + pos[l * H_ + f];
    v = (t != 0) ? v : 0.0f;
    __hip_bfloat16 h, lo;
    split2(v, h, lo);
    acc2[(size_t)m * (2 * H_) + f]      = h;
    acc2[(size_t)m * (2 * H_) + H_ + f] = lo;
}

// ------- weight transpose + f32->bf16x2: in [K][N] -> out [N][2K] (hi | lo) --------
__global__ void transpose_w_kernel(const float* __restrict__ in, __hip_bfloat16* __restrict__ out,
                                   int K, int N) {
    __shared__ float tile[32][33];
    int k0 = blockIdx.y * 32, n0 = blockIdx.x * 32;
    int tx = threadIdx.x, ty = threadIdx.y;
    #pragma unroll
    for (int i = ty; i < 32; i += 8)
        tile[i][tx] = in[(size_t)(k0 + i) * N + (n0 + tx)];
    __syncthreads();
    #pragma unroll
    for (int i = ty; i < 32; i += 8) {
        float v = tile[tx][i];
        __hip_bfloat16 h, lo;
        split2(v, h, lo);
        out[(size_t)(n0 + i) * (2 * K) + (k0 + tx)]     = h;
        out[(size_t)(n0 + i) * (2 * K) + K + (k0 + tx)] = lo;
    }
}

__global__ void bias_concat_kernel(const float* __restrict__ bq, const float* __restrict__ bk,
                                   const float* __restrict__ bv, float* __restrict__ out) {
    int i = blockIdx.x * 256 + threadIdx.x;
    if (i >= NL_ * QKVN) return;
    int l = i / QKVN, j = i - l * QKVN;
    float v = (j < 384) ? bq[l * 384 + j] : (j < 768 ? bk[l * 384 + j - 384] : bv[l * 384 + j - 768]);
    out[i] = v;
}

// ------ 3-term split-precision MFMA GEMM: C = A_hi@W_hi + A_hi@W_lo + A_lo@W_hi ----
// A2 [M][2K] hi|lo, Wt2 [N][2K] hi|lo; logical K-loop 3K with segment remap
// (A: [hi,hi,lo], W: [hi,lo,hi]); dropped lo@lo term ~2^-18 -> fp32-grade.
// 128x128 tile, BK=32, 4 waves 2x2, 2-phase double-buffered pipeline,
// bank-swizzled LDS (slot ^= (row&3)^((row>>2)&3), applied to BOTH the
// global_load_lds source AND the ds_read address - rule 21), bijective XCD swizzle.
// omode: 0 = f32 [M][N]; 1 = bf16x2 [M][2N] (hi|lo); 2 = bf16 [M][N].
__global__ __launch_bounds__(256) void gemm_bf16_kernel(
        const __hip_bfloat16* __restrict__ A2,
        const __hip_bfloat16* __restrict__ Wt2,
        const float* __restrict__ bias,
        void* __restrict__ outp, int omode,
        int N, int K, int act, int nbx) {
    __shared__ __hip_bfloat16 As[2][4096];
    __shared__ __hip_bfloat16 Bs[2][4096];
    int t = threadIdx.x;
    int lane = t & 63, wv = t >> 6;
    int wm = wv >> 1, wn = wv & 1;

    // bijective XCD-chunked swizzle (m204 form): contiguous grid chunk per XCD
    int nwg = gridDim.x;
    int q8 = nwg >> 3, r8 = nwg & 7;
    int xcd = blockIdx.x & 7, off = blockIdx.x >> 3;
    int swz = (xcd < r8 ? xcd * (q8 + 1) : r8 * (q8 + 1) + (xcd - r8) * q8) + off;
    int bn = (swz % nbx) * 128;
    int bm = (swz / nbx) * 128;

    const int Kst  = 2 * K;   // storage stride
    const int Kend = 3 * K;   // logical loop length
    f32x4 acc[4][4] = {};

    // staging: thread t covers half-tile row r=t>>2 (and r+64), 16B slot s=t&3.
    // inverse-swizzled global source so linear global_load_lds dest + swizzled
    // read form a consistent involution.
    int sr   = t >> 2;
    int sswz = (t & 3) ^ ((t >> 2) & 3) ^ ((t >> 4) & 3);
    const __hip_bfloat16* a_src = A2 + (size_t)(bm + sr) * Kst + sswz * 8;
    const __hip_bfloat16* b_src = Wt2 + (size_t)(bn + sr) * Kst + sswz * 8;

    // fragment read: row = 16*g + (lane&15), want slot = lane>>4 -> swizzled slot
    int slotp = (lane >> 4) ^ (lane & 3) ^ ((lane >> 2) & 3);
    int aOff = (wm * 64 + (lane & 15)) * 32 + slotp * 8;
    int bOff = (wn * 64 + (lane & 15)) * 32 + slotp * 8;

#define STAGE(buf, ak, wk) do { \
        gload_lds16(a_src + (ak), &As[buf][wv * 512]); \
        gload_lds16(a_src + (size_t)64 * Kst + (ak), &As[buf][2048 + wv * 512]); \
        gload_lds16(b_src + (wk), &Bs[buf][wv * 512]); \
        gload_lds16(b_src + (size_t)64 * Kst + (wk), &Bs[buf][2048 + wv * 512]); \
    } while (0)

    int nt = Kend >> 5;
    STAGE(0, 0, 0);
    __syncthreads();
    int cur = 0;
    for (int ti = 0; ti < nt; ++ti) {
        int k1 = (ti + 1) << 5;
        if (ti + 1 < nt) {                        // issue next-tile loads FIRST
            int ak = (k1 < K)     ? k1 : k1 - K;
            int wk = (k1 < 2 * K) ? k1 : k1 - 2 * K;
            STAGE(cur ^ 1, ak, wk);
        }
        short8 af[4], bf[4];
        #pragma unroll
        for (int m = 0; m < 4; ++m) af[m] = *(const short8*)(&As[cur][aOff + m * 512]);
        #pragma unroll
        for (int n = 0; n < 4; ++n) bf[n] = *(const short8*)(&Bs[cur][bOff + n * 512]);
        #pragma unroll
        for (int m = 0; m < 4; ++m)
            #pragma unroll
            for (int n = 0; n < 4; ++n)
                acc[m][n] = __builtin_amdgcn_mfma_f32_16x16x32_bf16(af[m], bf[n], acc[m][n], 0, 0, 0);
        __syncthreads();   // drains vmcnt: prefetched tile ready; reads done before overwrite
        cur ^= 1;
    }
#undef STAGE

    int colBase = bn + wn * 64 + (lane & 15);
    int rowBase = bm + wm * 64 + (lane >> 4) * 4;
    const float c0 = 0.7978845608f;  // sqrt(2/pi)
    #pragma unroll
    for (int n = 0; n < 4; ++n) {
        int c = colBase + n * 16;
        float bvv = bias[c];
        #pragma unroll
        for (int m = 0; m < 4; ++m) {
            int r0 = rowBase + m * 16;
            #pragma unroll
            for (int r = 0; r < 4; ++r) {
                float v = acc[m][n][r] + bvv;
                if (act == 1) {
                    float u = c0 * (v + 0.044715f * v * v * v);
                    v = v * 0.5f * (1.0f + tanhf(u));
                }
                size_t row = (size_t)(r0 + r);
                if (omode == 0) {
                    ((float*)outp)[row * N + c] = v;
                } else if (omode == 1) {
                    __hip_bfloat16 h, lo;
                    split2(v, h, lo);
                    ((__hip_bfloat16*)outp)[row * (2 * N) + c]     = h;
                    ((__hip_bfloat16*)outp)[row * (2 * N) + N + c] = lo;
                } else {
                    ((__hip_bfloat16*)outp)[row * N + c] = __float2bfloat16(v);
                }
            }
        }
    }
}

// ---------------- fused attention per (b, head): QK^T -> mask -> softmax -> PV ------
// qkv: [M][1152] bf16, interleaved split q[d]=qkv[d*12+nh], k at +384, v at +768.
// f32 math internally; output concat a2[row, nh*32+d] bf16x2 (hi | lo at +384).
__global__ __launch_bounds__(128) void attn_kernel(const __hip_bfloat16* __restrict__ qkv,
        const int* __restrict__ x, __hip_bfloat16* __restrict__ a2) {
    __shared__ float ks[L_][DH_ + 1];
    __shared__ float vs[L_][DH_];
    __shared__ float qs[50][DH_];
    __shared__ float es[50][L_ + 1];
    __shared__ int xb[L_];
    int tid = threadIdx.x;
    int b = blockIdx.x / NH_;
    int nh = blockIdx.x % NH_;
    const __hip_bfloat16* qb = qkv + (size_t)b * L_ * QKVN;

    for (int i = tid; i < L_ * DH_; i += 128) {
        int l = i >> 5, d = i & 31;
        ks[l][d] = __bfloat162float(qb[l * QKVN + 384 + d * NH_ + nh]);
        vs[l][d] = __bfloat162float(qb[l * QKVN + 768 + d * NH_ + nh]);
    }
    for (int i = tid; i < L_; i += 128) xb[i] = x[b * L_ + i];
    const float scale = 1.0f / sqrtf((float)H_);   // quirky: 1/sqrt(hidden_dim)

    for (int half = 0; half < 2; ++half) {
        __syncthreads();
        for (int i = tid; i < 50 * DH_; i += 128) {
            int l = i >> 5, d = i & 31;
            qs[l][d] = __bfloat162float(qb[(size_t)(half * 50 + l) * QKVN + d * NH_ + nh]);
        }
        __syncthreads();
        for (int i = tid; i < 50 * L_; i += 128) {
            int l = i / L_, m = i - l * L_;
            float s = 0.0f;
            #pragma unroll
            for (int d = 0; d < DH_; ++d) s += qs[l][d] * ks[m][d];
            es[l][m] = (xb[m] == 0) ? -1e10f : s * scale;
        }
        __syncthreads();
        if (tid < 50) {
            float mx = -INFINITY;
            for (int m2 = 0; m2 < L_; ++m2) mx = fmaxf(mx, es[tid][m2]);
            float sum = 0.0f;
            for (int m2 = 0; m2 < L_; ++m2) {
                float tt = expf(es[tid][m2] - mx);
                es[tid][m2] = tt;
                sum += tt;
            }
            float inv = 1.0f / sum;
            for (int m2 = 0; m2 < L_; ++m2) es[tid][m2] *= inv;
        }
        __syncthreads();
        for (int i = tid; i < 50 * DH_; i += 128) {
            int l = i >> 5, d = i & 31;
            float s = 0.0f;
            for (int m2 = 0; m2 < L_; ++m2) s += es[l][m2] * vs[m2][d];
            size_t row = (size_t)(b * L_ + half * 50 + l);
            __hip_bfloat16 h, lo;
            split2(s, h, lo);
            a2[row * (2 * H_) + nh * DH_ + d]      = h;
            a2[row * (2 * H_) + H_ + nh * DH_ + d] = lo;
        }
        __syncthreads();
    }
}

// ---------------- fused residual + LayerNorm (scalar g,b; ddof=1) * nonpad ---------
// X = Xf (f32), residual R2 (bf16x2 recon).
// MODE 0 (LN1): Y -> Y2 (bf16x2)
// MODE 1 (LN2): Y -> Yf (f32) ; acc2 = split(recon(acc2) + Y)
template <int MODE>
__global__ __launch_bounds__(128) void ln_kernel(
        const float* __restrict__ Xf,
        const __hip_bfloat16* __restrict__ R2,
        const int* __restrict__ x,
        const float* __restrict__ gp, const float* __restrict__ bp, int layer,
        float* __restrict__ Yf,
        __hip_bfloat16* __restrict__ Y2,
        __hip_bfloat16* __restrict__ acc2) {
    int row = blockIdx.x;
    int tid = threadIdx.x;
    size_t b1 = (size_t)row * H_;
    size_t b2 = (size_t)row * (2 * H_);

    float v[3];
    #pragma unroll
    for (int j = 0; j < 3; ++j) {
        int f = tid + j * 128;
        float r = __bfloat162float(R2[b2 + f]) + __bfloat162float(R2[b2 + H_ + f]);
        v[j] = Xf[b1 + f] + r;
    }

    __shared__ float red[2];
    float s = v[0] + v[1] + v[2];
    #pragma unroll
    for (int off = 32; off > 0; off >>= 1) s += __shfl_down(s, off);
    if ((tid & 63) == 0) red[tid >> 6] = s;
    __syncthreads();
    float mu = (red[0] + red[1]) * (1.0f / 384.0f);
    __syncthreads();

    float d[3];
    float qq = 0.0f;
    #pragma unroll
    for (int j = 0; j < 3; ++j) { d[j] = v[j] - mu; qq += d[j] * d[j]; }
    #pragma unroll
    for (int off = 32; off > 0; off >>= 1) qq += __shfl_down(qq, off);
    if ((tid & 63) == 0) red[tid >> 6] = qq;
    __syncthreads();
    float var = (red[0] + red[1]) * (1.0f / 383.0f);   // unbiased (ddof=1)
    float rstd = rsqrtf(var + 1e-8f);

    float g = gp[layer], bb = bp[layer];
    float np_ = (x[row] != 0) ? 1.0f : 0.0f;
    #pragma unroll
    for (int j = 0; j < 3; ++j) {
        int f = tid + j * 128;
        float y = (g * (d[j] * rstd) + bb) * np_;
        if (MODE == 0) {
            __hip_bfloat16 h, lo;
            split2(y, h, lo);
            Y2[b2 + f]      = h;
            Y2[b2 + H_ + f] = lo;
        } else {
            Yf[b1 + f] = y;
            float a = __bfloat162float(acc2[b2 + f]) + __bfloat162float(acc2[b2 + H_ + f]) + y;
            __hip_bfloat16 h, lo;
            split2(a, h, lo);
            acc2[b2 + f]      = h;
            acc2[b2 + H_ + f] = lo;
        }
    }
}

extern "C" void kernel_launch(void* const* d_in, const int* in_sizes, int n_in,
                              void* d_out, int out_size, void* d_ws, size_t ws_size,
                              hipStream_t stream) {
    const int*   x    = (const int*)d_in[0];
    const int*   seg  = (const int*)d_in[1];
    const float* tok  = (const float*)d_in[2];
    const float* sege = (const float*)d_in[3];
    const float* pos  = (const float*)d_in[4];
    const float* Wq   = (const float*)d_in[5];
    const float* bq   = (const float*)d_in[6];
    const float* Wk   = (const float*)d_in[7];
    const float* bk   = (const float*)d_in[8];
    const float* Wv   = (const float*)d_in[9];
    const float* bv   = (const float*)d_in[10];
    const float* Wo   = (const float*)d_in[11];
    const float* bo   = (const float*)d_in[12];
    const float* g1   = (const float*)d_in[13];
    const float* be1  = (const float*)d_in[14];
    const float* W1   = (const float*)d_in[15];
    const float* b1   = (const float*)d_in[16];
    const float* W2   = (const float*)d_in[17];
    const float* b2   = (const float*)d_in[18];
    const float* g2   = (const float*)d_in[19];
    const float* be2  = (const float*)d_in[20];

    // per-layer transposed bf16x2 weight layout within wTL (elements)
    const size_t OFF_Q  = 0;             // [384][768]
    const size_t OFF_K  = 294912;
    const size_t OFF_V  = 589824;
    const size_t OFF_WO = 884736;        // [384][768]
    const size_t OFF_W1 = 1179648;       // [1536][768]
    const size_t OFF_W2 = 2359296;       // [384][3072]

    // ---- workspace: header 85.7 MB + pool ----
    char* p = (char*)d_ws;
    __hip_bfloat16* wTL  = (__hip_bfloat16*)p; p += 7077888;      // per-layer weights (3,538,944 el)
    __hip_bfloat16* acc2 = (__hip_bfloat16*)p; p += 39321600;     // [M][768] hi|lo
    __hip_bfloat16* bE2  = (__hip_bfloat16*)p; p += 39321600;     // [M][768] hi|lo
    float* qkvb          = (float*)p;          p += 27648;        // concat qkv bias (all layers)
    char* pool           = p;
    // pool overlays (sequentially dead regions):
    //   qkvB [M][1152] bf16 (59.0 MB) | bA2 [M][768] bf16x2 at +59.0 MB (39.3 MB)
    //   woF  [M][384] f32 (39.3 MB, aliases dead qkvB)
    //   f2   [MC][3072] bf16x2 (157.3 MB full / 78.6 MB half; aliases dead qkvB/bA2/woF)
    __hip_bfloat16* qkvB = (__hip_bfloat16*)pool;
    __hip_bfloat16* bA2  = (__hip_bfloat16*)(pool + 58982400);
    float*          woF  = (float*)pool;
    __hip_bfloat16* f2   = (__hip_bfloat16*)pool;
    float* out = (float*)d_out;

    // FULL plan needs 243,035,136 B; MID (FFN 2-chunk) needs 184,052,736 B (< proven 200 MB).
    const int nch = (ws_size >= 243035136ULL) ? 1 : 2;
    const int MC  = M_ / nch;

    bias_concat_kernel<<<dim3((NL_ * QKVN + 255) / 256), dim3(256), 0, stream>>>(bq, bk, bv, qkvb);
    embed_kernel<<<dim3((M_ * H_ + 255) / 256), dim3(256), 0, stream>>>(x, seg, tok, sege, pos, acc2);

    dim3 blk(256), tb(32, 8);
    for (int l = 0; l < NL_; ++l) {
        // per-layer weight transpose into wTL (stream-ordered; prior layer done)
        transpose_w_kernel<<<dim3(12, 12), tb, 0, stream>>>(Wq + (size_t)l * H_ * H_,  wTL + OFF_Q,  H_,  H_);
        transpose_w_kernel<<<dim3(12, 12), tb, 0, stream>>>(Wk + (size_t)l * H_ * H_,  wTL + OFF_K,  H_,  H_);
        transpose_w_kernel<<<dim3(12, 12), tb, 0, stream>>>(Wv + (size_t)l * H_ * H_,  wTL + OFF_V,  H_,  H_);
        transpose_w_kernel<<<dim3(12, 12), tb, 0, stream>>>(Wo + (size_t)l * H_ * H_,  wTL + OFF_WO, H_,  H_);
        transpose_w_kernel<<<dim3(48, 12), tb, 0, stream>>>(W1 + (size_t)l * H_ * FF_, wTL + OFF_W1, H_,  FF_);
        transpose_w_kernel<<<dim3(12, 48), tb, 0, stream>>>(W2 + (size_t)l * FF_ * H_, wTL + OFF_W2, FF_, H_);

        const float* bol = bo + (size_t)l * H_;
        const float* b1l = b1 + (size_t)l * FF_;
        const float* b2l = b2 + (size_t)l * H_;

        // QKV: [M,384] 3-term -> qkvB bf16 (full M, 1800 blocks)
        gemm_bf16_kernel<<<dim3((QKVN / 128) * (M_ / 128)), blk, 0, stream>>>(
            acc2, wTL + OFF_Q, qkvb + (size_t)l * QKVN, qkvB, 2, QKVN, H_, 0, QKVN / 128);
        // attention (full M, 3072 blocks) -> bA2 bf16x2
        attn_kernel<<<dim3(B_ * NH_), dim3(128), 0, stream>>>(qkvB, x, bA2);
        // Wo -> woF f32 (600 blocks)
        gemm_bf16_kernel<<<dim3((H_ / 128) * (M_ / 128)), blk, 0, stream>>>(
            bA2, wTL + OFF_WO, bol, woF, 0, H_, H_, 0, H_ / 128);
        // LN1(woF + acc2) -> bE2
        ln_kernel<0><<<dim3(M_), dim3(128), 0, stream>>>(
            woF, acc2, x, g1, be1, l, nullptr, bE2, nullptr);
        // FFN (nch chunks): W1(+gelu) -> f2 ; W2 -> out rows
        for (int ch = 0; ch < nch; ++ch) {
            gemm_bf16_kernel<<<dim3((FF_ / 128) * (MC / 128)), blk, 0, stream>>>(
                bE2 + (size_t)ch * MC * 2 * H_, wTL + OFF_W1, b1l, f2, 1, FF_, H_, 1, FF_ / 128);
            gemm_bf16_kernel<<<dim3((H_ / 128) * (MC / 128)), blk, 0, stream>>>(
                f2, wTL + OFF_W2, b2l, out + (size_t)ch * MC * H_, 0, H_, FF_, 0, H_ / 128);
        }
        // LN2(out + bE2) -> out ; acc2 = split(recon(acc2) + out)
        ln_kernel<1><<<dim3(M_), dim3(128), 0, stream>>>(
            out, bE2, x, g2, be2, l, out, nullptr, acc2);
    }
}

// Round 8
// 3515.182 us; speedup vs baseline: 3.0822x; 1.5136x over previous
//
#include <hip/hip_runtime.h>
#include <hip/hip_bf16.h>
#include <math.h>

#define B_  256
#define L_  100
#define H_  384
#define NH_ 12
#define DH_ 32
#define NL_ 6
#define FF_ 1536
#define M_  (B_*L_)   // 25600 rows
#define QKVN 1152     // 3*H

typedef __attribute__((ext_vector_type(8))) short short8;
typedef __attribute__((ext_vector_type(4))) float f32x4;

#define GLOBAL_AS __attribute__((address_space(1)))
#define LDS_AS    __attribute__((address_space(3)))

__device__ __forceinline__ void gload_lds16(const void* g, void* l) {
    __builtin_amdgcn_global_load_lds((const GLOBAL_AS void*)g, (LDS_AS void*)l, 16, 0, 0);
}

__device__ __forceinline__ void split2(float v, __hip_bfloat16& hi, __hip_bfloat16& lo) {
    hi = __float2bfloat16(v);
    lo = __float2bfloat16(v - __bfloat162float(hi));
}

__device__ __forceinline__ unsigned short f2b(float v) {
    __hip_bfloat16 h = __float2bfloat16(v);
    return *(unsigned short*)&h;
}

// ---------------- embedding: acc2 = split(tok[x] + seg[s] + pos[l]) * nonpad -------
__global__ void embed_kernel(const int* __restrict__ x, const int* __restrict__ seg,
                             const float* __restrict__ tok, const float* __restrict__ sege,
                             const float* __restrict__ pos,
                             __hip_bfloat16* __restrict__ acc2) {
    int idx = blockIdx.x * blockDim.x + threadIdx.x;
    if (idx >= M_ * H_) return;
    int m = idx / H_;
    int f = idx - m * H_;
    int t = x[m];
    int s = seg[m];
    int l = m % L_;
    float v = tok[t * H_ + f] + sege[s * H_ + f] + pos[l * H_ + f];
    v = (t != 0) ? v : 0.0f;
    __hip_bfloat16 h, lo;
    split2(v, h, lo);
    acc2[(size_t)m * (2 * H_) + f]      = h;
    acc2[(size_t)m * (2 * H_) + H_ + f] = lo;
}

// ------- weight transpose + f32->bf16x2: in [K][N] -> out [N][2K] (hi | lo) --------
// PERM=1: output row permuted j -> (j%12)*32 + j/12 (head-major QKV layout)
template <int PERM>
__global__ void transpose_w_kernel(const float* __restrict__ in, __hip_bfloat16* __restrict__ out,
                                   int K, int N) {
    __shared__ float tile[32][33];
    int k0 = blockIdx.y * 32, n0 = blockIdx.x * 32;
    int tx = threadIdx.x, ty = threadIdx.y;
    #pragma unroll
    for (int i = ty; i < 32; i += 8)
        tile[i][tx] = in[(size_t)(k0 + i) * N + (n0 + tx)];
    __syncthreads();
    #pragma unroll
    for (int i = ty; i < 32; i += 8) {
        float v = tile[tx][i];
        __hip_bfloat16 h, lo;
        split2(v, h, lo);
        int j = n0 + i;
        int jo = PERM ? ((j % 12) * 32 + j / 12) : j;
        out[(size_t)jo * (2 * K) + (k0 + tx)]     = h;
        out[(size_t)jo * (2 * K) + K + (k0 + tx)] = lo;
    }
}

// bias concat with head-major permutation: out col j' = t*384 + nh*32 + d
__global__ void bias_concat_kernel(const float* __restrict__ bq, const float* __restrict__ bk,
                                   const float* __restrict__ bv, float* __restrict__ out) {
    int i = blockIdx.x * 256 + threadIdx.x;
    if (i >= NL_ * QKVN) return;
    int l = i / QKVN, jp = i - l * QKVN;
    int t = jp / 384, r = jp % 384;
    int h = r >> 5, d = r & 31;
    int j = d * 12 + h;  // original (interleaved) column
    float v = (t == 0) ? bq[l * 384 + j] : (t == 1 ? bk[l * 384 + j] : bv[l * 384 + j]);
    out[i] = v;
}

// ------ 3-term split-precision MFMA GEMM: C = A_hi@W_hi + A_hi@W_lo + A_lo@W_hi ----
// (unchanged from R5, which passed) 128x128, BK=32, 2-phase dbuf, swizzled LDS.
__global__ __launch_bounds__(256) void gemm_bf16_kernel(
        const __hip_bfloat16* __restrict__ A2,
        const __hip_bfloat16* __restrict__ Wt2,
        const float* __restrict__ bias,
        void* __restrict__ outp, int omode,
        int N, int K, int act, int nbx) {
    __shared__ __hip_bfloat16 As[2][4096];
    __shared__ __hip_bfloat16 Bs[2][4096];
    int t = threadIdx.x;
    int lane = t & 63, wv = t >> 6;
    int wm = wv >> 1, wn = wv & 1;

    int nwg = gridDim.x;
    int q8 = nwg >> 3, r8 = nwg & 7;
    int xcd = blockIdx.x & 7, off = blockIdx.x >> 3;
    int swz = (xcd < r8 ? xcd * (q8 + 1) : r8 * (q8 + 1) + (xcd - r8) * q8) + off;
    int bn = (swz % nbx) * 128;
    int bm = (swz / nbx) * 128;

    const int Kst  = 2 * K;
    const int Kend = 3 * K;
    f32x4 acc[4][4] = {};

    int sr   = t >> 2;
    int sswz = (t & 3) ^ ((t >> 2) & 3) ^ ((t >> 4) & 3);
    const __hip_bfloat16* a_src = A2 + (size_t)(bm + sr) * Kst + sswz * 8;
    const __hip_bfloat16* b_src = Wt2 + (size_t)(bn + sr) * Kst + sswz * 8;

    int slotp = (lane >> 4) ^ (lane & 3) ^ ((lane >> 2) & 3);
    int aOff = (wm * 64 + (lane & 15)) * 32 + slotp * 8;
    int bOff = (wn * 64 + (lane & 15)) * 32 + slotp * 8;

#define STAGE(buf, ak, wk) do { \
        gload_lds16(a_src + (ak), &As[buf][wv * 512]); \
        gload_lds16(a_src + (size_t)64 * Kst + (ak), &As[buf][2048 + wv * 512]); \
        gload_lds16(b_src + (wk), &Bs[buf][wv * 512]); \
        gload_lds16(b_src + (size_t)64 * Kst + (wk), &Bs[buf][2048 + wv * 512]); \
    } while (0)

    int nt = Kend >> 5;
    STAGE(0, 0, 0);
    __syncthreads();
    int cur = 0;
    for (int ti = 0; ti < nt; ++ti) {
        int k1 = (ti + 1) << 5;
        if (ti + 1 < nt) {
            int ak = (k1 < K)     ? k1 : k1 - K;
            int wk = (k1 < 2 * K) ? k1 : k1 - 2 * K;
            STAGE(cur ^ 1, ak, wk);
        }
        short8 af[4], bf[4];
        #pragma unroll
        for (int m = 0; m < 4; ++m) af[m] = *(const short8*)(&As[cur][aOff + m * 512]);
        #pragma unroll
        for (int n = 0; n < 4; ++n) bf[n] = *(const short8*)(&Bs[cur][bOff + n * 512]);
        #pragma unroll
        for (int m = 0; m < 4; ++m)
            #pragma unroll
            for (int n = 0; n < 4; ++n)
                acc[m][n] = __builtin_amdgcn_mfma_f32_16x16x32_bf16(af[m], bf[n], acc[m][n], 0, 0, 0);
        __syncthreads();
        cur ^= 1;
    }
#undef STAGE

    int colBase = bn + wn * 64 + (lane & 15);
    int rowBase = bm + wm * 64 + (lane >> 4) * 4;
    const float c0 = 0.7978845608f;
    #pragma unroll
    for (int n = 0; n < 4; ++n) {
        int c = colBase + n * 16;
        float bvv = bias[c];
        #pragma unroll
        for (int m = 0; m < 4; ++m) {
            int r0 = rowBase + m * 16;
            #pragma unroll
            for (int r = 0; r < 4; ++r) {
                float v = acc[m][n][r] + bvv;
                if (act == 1) {
                    float u = c0 * (v + 0.044715f * v * v * v);
                    v = v * 0.5f * (1.0f + tanhf(u));
                }
                size_t row = (size_t)(r0 + r);
                if (omode == 0) {
                    ((float*)outp)[row * N + c] = v;
                } else if (omode == 1) {
                    __hip_bfloat16 h, lo;
                    split2(v, h, lo);
                    ((__hip_bfloat16*)outp)[row * (2 * N) + c]     = h;
                    ((__hip_bfloat16*)outp)[row * (2 * N) + N + c] = lo;
                } else {
                    ((__hip_bfloat16*)outp)[row * N + c] = __float2bfloat16(v);
                }
            }
        }
    }
}

// ---------------- MFMA attention per (b, nh) ----------------------------------------
// qkvP: [M][1152] bf16, HEAD-MAJOR: q at nh*32+d, k at 384+nh*32+d, v at 768+nh*32+d.
// S = Q@K^T via 16x16x32 MFMA (K=DH=32 exact); in-register softmax on C-frag layout
// (row=(lane>>4)*4+r, col=lane&15, shfl_xor width-16 row reduce); P->LDS bf16; PV MFMA
// with V^T in LDS. Output a2[row, nh*32+d] bf16x2 (hi | lo at +384).
__global__ __launch_bounds__(256) void attn_kernel(const __hip_bfloat16* __restrict__ qkvP,
        const int* __restrict__ x, __hip_bfloat16* __restrict__ a2) {
    __shared__ unsigned short qs[112][32];   // Q rows (pad 100-111 garbage: rows discarded)
    __shared__ unsigned short ks[128][32];   // K rows (pad 100-127 garbage: cols masked)
    __shared__ unsigned short vst[32][136];  // V^T [d][kv]; kv 100-127 ZEROED (NaN safety)
    __shared__ unsigned short ps[112][136];  // P bf16 (unnormalized)
    __shared__ int xb[128];
    int t = threadIdx.x;
    int lane = t & 63, wv = t >> 6;
    int b = blockIdx.x / NH_;
    int nh = blockIdx.x % NH_;
    const __hip_bfloat16* base = qkvP + (size_t)b * L_ * QKVN;

    // zero vst pad cols 100..135 (word-disjoint from data cols 0..99)
    for (int i = t; i < 576; i += 256) {
        int d = i / 18, w = i % 18;
        ((int*)vst)[d * 68 + 50 + w] = 0;
    }
    for (int i = t; i < 128; i += 256) xb[i] = (i < L_) ? x[b * L_ + i] : 0;

    // stage Q (7x16 rows) and K (8x16 rows) via global_load_lds, inverse-swizzled src
    {
        int r16 = lane >> 2, s = lane & 3;
        for (int i = wv; i < 7; i += 4) {
            int row = i * 16 + r16;
            int sp = s ^ (row & 3) ^ ((row >> 2) & 3);
            gload_lds16(base + (size_t)row * QKVN + nh * 32 + sp * 8, &qs[i * 16][0]);
        }
        for (int i = wv; i < 8; i += 4) {
            int row = i * 16 + r16;
            int sp = s ^ (row & 3) ^ ((row >> 2) & 3);
            gload_lds16(base + (size_t)row * QKVN + 384 + nh * 32 + sp * 8, &ks[i * 16][0]);
        }
    }
    // stage V transposed (reg path; rows kv<100 only)
    if (t < 200) {
        int kv = t >> 1, d0 = (t & 1) * 16;
        const __hip_bfloat16* vsrc = base + (size_t)kv * QKVN + 768 + nh * 32 + d0;
        short8 v0 = *(const short8*)vsrc;
        short8 v1 = *(const short8*)(vsrc + 8);
        #pragma unroll
        for (int j = 0; j < 8; ++j) {
            vst[d0 + j][kv]     = (unsigned short)v0[j];
            vst[d0 + 8 + j][kv] = (unsigned short)v1[j];
        }
    }
    __syncthreads();

    const float scale = 1.0f / sqrtf((float)H_);   // quirky: 1/sqrt(hidden_dim)
    int n = lane & 15, g = lane >> 4;

    for (int rt = wv; rt < 7; rt += 4) {
        // ---- S = Q@K^T : 8 col-tiles ----
        int arow = rt * 16 + n;
        int asp = (g ^ (arow & 3) ^ ((arow >> 2) & 3)) * 8;
        short8 aq = *(const short8*)&qs[arow][asp];
        f32x4 s8[8];
        #pragma unroll
        for (int ct = 0; ct < 8; ++ct) {
            int brow = ct * 16 + n;
            int bsp = (g ^ (brow & 3) ^ ((brow >> 2) & 3)) * 8;
            short8 bk = *(const short8*)&ks[brow][bsp];
            f32x4 z = {0.0f, 0.0f, 0.0f, 0.0f};
            s8[ct] = __builtin_amdgcn_mfma_f32_16x16x32_bf16(aq, bk, z, 0, 0, 0);
        }
        // ---- scale + mask (reference: e*scale then where(x==0, -1e10); pads -> -inf)
        #pragma unroll
        for (int ct = 0; ct < 8; ++ct) {
            int col = ct * 16 + n;
            int xv = xb[col];
            #pragma unroll
            for (int r = 0; r < 4; ++r) {
                float v = s8[ct][r] * scale;
                v = (xv == 0) ? -1e10f : v;
                v = (col >= L_) ? -INFINITY : v;
                s8[ct][r] = v;
            }
        }
        // ---- in-register row softmax (unnormalized P; defer /sum to O) ----
        float sm[4];
        #pragma unroll
        for (int r = 0; r < 4; ++r) {
            float m = s8[0][r];
            #pragma unroll
            for (int ct = 1; ct < 8; ++ct) m = fmaxf(m, s8[ct][r]);
            m = fmaxf(m, __shfl_xor(m, 1, 16));
            m = fmaxf(m, __shfl_xor(m, 2, 16));
            m = fmaxf(m, __shfl_xor(m, 4, 16));
            m = fmaxf(m, __shfl_xor(m, 8, 16));
            float s = 0.0f;
            #pragma unroll
            for (int ct = 0; ct < 8; ++ct) {
                float p = __expf(s8[ct][r] - m);
                s8[ct][r] = p;
                s += p;
            }
            s += __shfl_xor(s, 1, 16);
            s += __shfl_xor(s, 2, 16);
            s += __shfl_xor(s, 4, 16);
            s += __shfl_xor(s, 8, 16);
            sm[r] = s;
        }
        // ---- P -> LDS (bf16) ----
        int prow = rt * 16 + g * 4;
        #pragma unroll
        for (int ct = 0; ct < 8; ++ct) {
            int col = ct * 16 + n;
            #pragma unroll
            for (int r = 0; r < 4; ++r)
                ps[prow + r][col] = f2b(s8[ct][r]);
        }
        // ---- O = P@V : 2 d-tiles x 4 k-steps ----
        f32x4 o0 = {0.0f, 0.0f, 0.0f, 0.0f}, o1 = o0;
        #pragma unroll
        for (int kt = 0; kt < 4; ++kt) {
            short8 pa = *(const short8*)&ps[rt * 16 + n][kt * 32 + g * 8];
            short8 b0 = *(const short8*)&vst[n][kt * 32 + g * 8];
            short8 b1 = *(const short8*)&vst[16 + n][kt * 32 + g * 8];
            o0 = __builtin_amdgcn_mfma_f32_16x16x32_bf16(pa, b0, o0, 0, 0, 0);
            o1 = __builtin_amdgcn_mfma_f32_16x16x32_bf16(pa, b1, o1, 0, 0, 0);
        }
        // ---- normalize + write (bf16x2) ----
        #pragma unroll
        for (int r = 0; r < 4; ++r) {
            int lrow = prow + r;
            if (lrow < L_) {
                size_t row = (size_t)b * L_ + lrow;
                float inv = 1.0f / sm[r];
                __hip_bfloat16 h, lo;
                float v0 = o0[r] * inv;
                split2(v0, h, lo);
                a2[row * (2 * H_) + nh * DH_ + n]      = h;
                a2[row * (2 * H_) + H_ + nh * DH_ + n] = lo;
                float v1 = o1[r] * inv;
                split2(v1, h, lo);
                a2[row * (2 * H_) + nh * DH_ + 16 + n]      = h;
                a2[row * (2 * H_) + H_ + nh * DH_ + 16 + n] = lo;
            }
        }
    }
}

// ---------------- fused residual + LayerNorm (scalar g,b; ddof=1) * nonpad ---------
template <int MODE>
__global__ __launch_bounds__(128) void ln_kernel(
        const float* __restrict__ Xf,
        const __hip_bfloat16* __restrict__ R2,
        const int* __restrict__ x,
        const float* __restrict__ gp, const float* __restrict__ bp, int layer,
        float* __restrict__ Yf,
        __hip_bfloat16* __restrict__ Y2,
        __hip_bfloat16* __restrict__ acc2) {
    int row = blockIdx.x;
    int tid = threadIdx.x;
    size_t b1 = (size_t)row * H_;
    size_t b2 = (size_t)row * (2 * H_);

    float v[3];
    #pragma unroll
    for (int j = 0; j < 3; ++j) {
        int f = tid + j * 128;
        float r = __bfloat162float(R2[b2 + f]) + __bfloat162float(R2[b2 + H_ + f]);
        v[j] = Xf[b1 + f] + r;
    }

    __shared__ float red[2];
    float s = v[0] + v[1] + v[2];
    #pragma unroll
    for (int off = 32; off > 0; off >>= 1) s += __shfl_down(s, off);
    if ((tid & 63) == 0) red[tid >> 6] = s;
    __syncthreads();
    float mu = (red[0] + red[1]) * (1.0f / 384.0f);
    __syncthreads();

    float d[3];
    float qq = 0.0f;
    #pragma unroll
    for (int j = 0; j < 3; ++j) { d[j] = v[j] - mu; qq += d[j] * d[j]; }
    #pragma unroll
    for (int off = 32; off > 0; off >>= 1) qq += __shfl_down(qq, off);
    if ((tid & 63) == 0) red[tid >> 6] = qq;
    __syncthreads();
    float var = (red[0] + red[1]) * (1.0f / 383.0f);
    float rstd = rsqrtf(var + 1e-8f);

    float g = gp[layer], bb = bp[layer];
    float np_ = (x[row] != 0) ? 1.0f : 0.0f;
    #pragma unroll
    for (int j = 0; j < 3; ++j) {
        int f = tid + j * 128;
        float y = (g * (d[j] * rstd) + bb) * np_;
        if (MODE == 0) {
            __hip_bfloat16 h, lo;
            split2(y, h, lo);
            Y2[b2 + f]      = h;
            Y2[b2 + H_ + f] = lo;
        } else {
            Yf[b1 + f] = y;
            float a = __bfloat162float(acc2[b2 + f]) + __bfloat162float(acc2[b2 + H_ + f]) + y;
            __hip_bfloat16 h, lo;
            split2(a, h, lo);
            acc2[b2 + f]      = h;
            acc2[b2 + H_ + f] = lo;
        }
    }
}

extern "C" void kernel_launch(void* const* d_in, const int* in_sizes, int n_in,
                              void* d_out, int out_size, void* d_ws, size_t ws_size,
                              hipStream_t stream) {
    const int*   x    = (const int*)d_in[0];
    const int*   seg  = (const int*)d_in[1];
    const float* tok  = (const float*)d_in[2];
    const float* sege = (const float*)d_in[3];
    const float* pos  = (const float*)d_in[4];
    const float* Wq   = (const float*)d_in[5];
    const float* bq   = (const float*)d_in[6];
    const float* Wk   = (const float*)d_in[7];
    const float* bk   = (const float*)d_in[8];
    const float* Wv   = (const float*)d_in[9];
    const float* bv   = (const float*)d_in[10];
    const float* Wo   = (const float*)d_in[11];
    const float* bo   = (const float*)d_in[12];
    const float* g1   = (const float*)d_in[13];
    const float* be1  = (const float*)d_in[14];
    const float* W1   = (const float*)d_in[15];
    const float* b1   = (const float*)d_in[16];
    const float* W2   = (const float*)d_in[17];
    const float* b2   = (const float*)d_in[18];
    const float* g2   = (const float*)d_in[19];
    const float* be2  = (const float*)d_in[20];

    const size_t OFF_Q  = 0;
    const size_t OFF_K  = 294912;
    const size_t OFF_V  = 589824;
    const size_t OFF_WO = 884736;
    const size_t OFF_W1 = 1179648;
    const size_t OFF_W2 = 2359296;

    char* p = (char*)d_ws;
    __hip_bfloat16* wTL  = (__hip_bfloat16*)p; p += 7077888;
    __hip_bfloat16* acc2 = (__hip_bfloat16*)p; p += 39321600;
    __hip_bfloat16* bE2  = (__hip_bfloat16*)p; p += 39321600;
    float* qkvb          = (float*)p;          p += 27648;
    char* pool           = p;
    __hip_bfloat16* qkvP = (__hip_bfloat16*)pool;                 // [M][1152] bf16 head-major
    __hip_bfloat16* bA2  = (__hip_bfloat16*)(pool + 58982400);    // [M][768] bf16x2
    float*          woF  = (float*)pool;                          // aliases dead qkvP
    __hip_bfloat16* f2   = (__hip_bfloat16*)pool;                 // aliases pool after LN1
    float* out = (float*)d_out;

    const int nch = (ws_size >= 243035136ULL) ? 1 : 2;
    const int MC  = M_ / nch;

    bias_concat_kernel<<<dim3((NL_ * QKVN + 255) / 256), dim3(256), 0, stream>>>(bq, bk, bv, qkvb);
    embed_kernel<<<dim3((M_ * H_ + 255) / 256), dim3(256), 0, stream>>>(x, seg, tok, sege, pos, acc2);

    dim3 blk(256), tb(32, 8);
    for (int l = 0; l < NL_; ++l) {
        transpose_w_kernel<1><<<dim3(12, 12), tb, 0, stream>>>(Wq + (size_t)l * H_ * H_,  wTL + OFF_Q,  H_,  H_);
        transpose_w_kernel<1><<<dim3(12, 12), tb, 0, stream>>>(Wk + (size_t)l * H_ * H_,  wTL + OFF_K,  H_,  H_);
        transpose_w_kernel<1><<<dim3(12, 12), tb, 0, stream>>>(Wv + (size_t)l * H_ * H_,  wTL + OFF_V,  H_,  H_);
        transpose_w_kernel<0><<<dim3(12, 12), tb, 0, stream>>>(Wo + (size_t)l * H_ * H_,  wTL + OFF_WO, H_,  H_);
        transpose_w_kernel<0><<<dim3(48, 12), tb, 0, stream>>>(W1 + (size_t)l * H_ * FF_, wTL + OFF_W1, H_,  FF_);
        transpose_w_kernel<0><<<dim3(12, 48), tb, 0, stream>>>(W2 + (size_t)l * FF_ * H_, wTL + OFF_W2, FF_, H_);

        const float* bol = bo + (size_t)l * H_;
        const float* b1l = b1 + (size_t)l * FF_;
        const float* b2l = b2 + (size_t)l * H_;

        // QKV (head-major cols) -> qkvP bf16
        gemm_bf16_kernel<<<dim3((QKVN / 128) * (M_ / 128)), blk, 0, stream>>>(
            acc2, wTL + OFF_Q, qkvb + (size_t)l * QKVN, qkvP, 2, QKVN, H_, 0, QKVN / 128);
        // MFMA attention -> bA2 bf16x2
        attn_kernel<<<dim3(B_ * NH_), dim3(256), 0, stream>>>(qkvP, x, bA2);
        // Wo -> woF f32
        gemm_bf16_kernel<<<dim3((H_ / 128) * (M_ / 128)), blk, 0, stream>>>(
            bA2, wTL + OFF_WO, bol, woF, 0, H_, H_, 0, H_ / 128);
        // LN1(woF + acc2) -> bE2
        ln_kernel<0><<<dim3(M_), dim3(128), 0, stream>>>(
            woF, acc2, x, g1, be1, l, nullptr, bE2, nullptr);
        // FFN
        for (int ch = 0; ch < nch; ++ch) {
            gemm_bf16_kernel<<<dim3((FF_ / 128) * (MC / 128)), blk, 0, stream>>>(
                bE2 + (size_t)ch * MC * 2 * H_, wTL + OFF_W1, b1l, f2, 1, FF_, H_, 1, FF_ / 128);
            gemm_bf16_kernel<<<dim3((H_ / 128) * (MC / 128)), blk, 0, stream>>>(
                f2, wTL + OFF_W2, b2l, out + (size_t)ch * MC * H_, 0, H_, FF_, 0, H_ / 128);
        }
        // LN2(out + bE2) -> out ; acc2 update
        ln_kernel<1><<<dim3(M_), dim3(128), 0, stream>>>(
            out, bE2, x, g2, be2, l, out, nullptr, acc2);
    }
}

// Round 9
// 3230.853 us; speedup vs baseline: 3.3534x; 1.0880x over previous
//
#include <hip/hip_runtime.h>
#include <hip/hip_bf16.h>
#include <math.h>

#define B_  256
#define L_  100
#define H_  384
#define NH_ 12
#define DH_ 32
#define NL_ 6
#define FF_ 1536
#define M_  (B_*L_)   // 25600 rows
#define QKVN 1152     // 3*H

// per-layer transposed bf16x2 weight layout within wTL (elements)
#define OFF_Q  0
#define OFF_K  294912
#define OFF_V  589824
#define OFF_WO 884736
#define OFF_W1 1179648
#define OFF_W2 2359296

typedef __attribute__((ext_vector_type(8))) short short8;
typedef __attribute__((ext_vector_type(4))) float f32x4;

#define GLOBAL_AS __attribute__((address_space(1)))
#define LDS_AS    __attribute__((address_space(3)))

__device__ __forceinline__ void gload_lds16(const void* g, void* l) {
    __builtin_amdgcn_global_load_lds((const GLOBAL_AS void*)g, (LDS_AS void*)l, 16, 0, 0);
}

__device__ __forceinline__ void split2(float v, __hip_bfloat16& hi, __hip_bfloat16& lo) {
    hi = __float2bfloat16(v);
    lo = __float2bfloat16(v - __bfloat162float(hi));
}

__device__ __forceinline__ unsigned short f2b(float v) {
    __hip_bfloat16 h = __float2bfloat16(v);
    return *(unsigned short*)&h;
}

// ---------------- embedding: acc2 = split(tok[x] + seg[s] + pos[l]) * nonpad -------
__global__ void embed_kernel(const int* __restrict__ x, const int* __restrict__ seg,
                             const float* __restrict__ tok, const float* __restrict__ sege,
                             const float* __restrict__ pos,
                             __hip_bfloat16* __restrict__ acc2) {
    int idx = blockIdx.x * blockDim.x + threadIdx.x;
    if (idx >= M_ * H_) return;
    int m = idx / H_;
    int f = idx - m * H_;
    int t = x[m];
    int s = seg[m];
    int l = m % L_;
    float v = tok[t * H_ + f] + sege[s * H_ + f] + pos[l * H_ + f];
    v = (t != 0) ? v : 0.0f;
    __hip_bfloat16 h, lo;
    split2(v, h, lo);
    acc2[(size_t)m * (2 * H_) + f]      = h;
    acc2[(size_t)m * (2 * H_) + H_ + f] = lo;
}

// ------ fused per-layer weight prep: all 6 transposes (f32 -> bf16x2 [N][2K]) ------
// Q/K/V output rows permuted j -> (j%12)*32 + j/12 (head-major).
__global__ void transpose_all_kernel(const float* __restrict__ Wq, const float* __restrict__ Wk,
        const float* __restrict__ Wv, const float* __restrict__ Wo,
        const float* __restrict__ W1, const float* __restrict__ W2,
        __hip_bfloat16* __restrict__ wTL) {
    __shared__ float tile[32][33];
    int bid = blockIdx.x;
    const float* src;
    __hip_bfloat16* dst;
    int K, N, nx, tix, perm = 0;
    if (bid < 432) {               // Q,K,V: 3 x 144 tiles
        int m = bid / 144; tix = bid % 144;
        src = (m == 0) ? Wq : (m == 1 ? Wk : Wv);
        dst = wTL + (m == 0 ? OFF_Q : (m == 1 ? OFF_K : OFF_V));
        K = 384; N = 384; nx = 12; perm = 1;
    } else if (bid < 576) {        // Wo: 144
        tix = bid - 432; src = Wo; dst = wTL + OFF_WO; K = 384; N = 384; nx = 12;
    } else if (bid < 1152) {       // W1: 576
        tix = bid - 576; src = W1; dst = wTL + OFF_W1; K = 384; N = 1536; nx = 48;
    } else {                       // W2: 576
        tix = bid - 1152; src = W2; dst = wTL + OFF_W2; K = 1536; N = 384; nx = 12;
    }
    int n0 = (tix % nx) * 32, k0 = (tix / nx) * 32;
    int tx = threadIdx.x, ty = threadIdx.y;
    #pragma unroll
    for (int i = ty; i < 32; i += 8)
        tile[i][tx] = src[(size_t)(k0 + i) * N + (n0 + tx)];
    __syncthreads();
    #pragma unroll
    for (int i = ty; i < 32; i += 8) {
        float v = tile[tx][i];
        __hip_bfloat16 h, lo;
        split2(v, h, lo);
        int j = n0 + i;
        int jo = perm ? ((j % 12) * 32 + j / 12) : j;
        dst[(size_t)jo * (2 * K) + (k0 + tx)]     = h;
        dst[(size_t)jo * (2 * K) + K + (k0 + tx)] = lo;
    }
}

// bias concat with head-major permutation: out col j' = t*384 + nh*32 + d
__global__ void bias_concat_kernel(const float* __restrict__ bq, const float* __restrict__ bk,
                                   const float* __restrict__ bv, float* __restrict__ out) {
    int i = blockIdx.x * 256 + threadIdx.x;
    if (i >= NL_ * QKVN) return;
    int l = i / QKVN, jp = i - l * QKVN;
    int t = jp / 384, r = jp % 384;
    int h = r >> 5, d = r & 31;
    int j = d * 12 + h;  // original (interleaved) column
    float v = (t == 0) ? bq[l * 384 + j] : (t == 1 ? bk[l * 384 + j] : bv[l * 384 + j]);
    out[i] = v;
}

// ------ 3-term split-precision MFMA GEMM: C = A_hi@W_hi + A_hi@W_lo + A_lo@W_hi ----
// A2 [M][2K] hi|lo, Wt2 [N][2K] hi|lo; logical K-loop 3K with segment remap
// (A: [hi,hi,lo], W: [hi,lo,hi]); dropped lo@lo ~2^-18 -> fp32-grade products.
// BIG=1: 256x128 tile, 8 waves (512 thr). BIG=0: 128x128, 4 waves (256 thr).
// 2-phase double-buffered pipeline; swizzled LDS (inverse-swizzled gload source +
// swizzled ds_read, rule 21); bijective XCD swizzle. TAG only names the dispatch.
// omode: 0 = f32 [M][N]; 1 = bf16x2 [M][2N]; 2 = bf16 [M][N].
template <int TAG, int BIG>
__global__ __launch_bounds__(512) void gemm_bf16_kernel(
        const __hip_bfloat16* __restrict__ A2,
        const __hip_bfloat16* __restrict__ Wt2,
        const float* __restrict__ bias,
        void* __restrict__ outp, int omode,
        int N, int K, int act, int nbx) {
    constexpr int BM = BIG ? 256 : 128;
    __shared__ __hip_bfloat16 As[2][BM * 32];
    __shared__ __hip_bfloat16 Bs[2][128 * 32];
    int t = threadIdx.x;
    int lane = t & 63, wv = t >> 6;
    int wm = wv >> 1, wn = wv & 1;

    int nwg = gridDim.x;
    int q8 = nwg >> 3, r8 = nwg & 7;
    int xcd = blockIdx.x & 7, off = blockIdx.x >> 3;
    int swz = (xcd < r8 ? xcd * (q8 + 1) : r8 * (q8 + 1) + (xcd - r8) * q8) + off;
    int bn = (swz % nbx) * 128;
    int bm = (swz / nbx) * BM;

    const int Kst  = 2 * K;
    const int Kend = 3 * K;
    f32x4 acc[4][4] = {};

    int sr   = t >> 2;
    int sswz = (t & 3) ^ ((t >> 2) & 3) ^ ((t >> 4) & 3);
    const __hip_bfloat16* a_src = A2 + (size_t)(bm + sr) * Kst + sswz * 8;
    const __hip_bfloat16* b_src = Wt2 + (size_t)(bn + sr) * Kst + sswz * 8;

    int slotp = (lane >> 4) ^ (lane & 3) ^ ((lane >> 2) & 3);
    int aOff = (wm * 64 + (lane & 15)) * 32 + slotp * 8;
    int bOff = (wn * 64 + (lane & 15)) * 32 + slotp * 8;

#define STAGE(buf, ak, wk) do { \
        gload_lds16(a_src + (ak), &As[buf][wv * 512]); \
        gload_lds16(a_src + (size_t)(BM / 2) * Kst + (ak), &As[buf][(BM / 2) * 32 + wv * 512]); \
        gload_lds16(b_src + (wk), &Bs[buf][wv * 512]); \
        if (!BIG) gload_lds16(b_src + (size_t)64 * Kst + (wk), &Bs[buf][2048 + wv * 512]); \
    } while (0)

    int nt = Kend >> 5;
    STAGE(0, 0, 0);
    __syncthreads();
    int cur = 0;
    for (int ti = 0; ti < nt; ++ti) {
        int k1 = (ti + 1) << 5;
        if (ti + 1 < nt) {                        // issue next-tile loads FIRST
            int ak = (k1 < K)     ? k1 : k1 - K;
            int wk = (k1 < 2 * K) ? k1 : k1 - 2 * K;
            STAGE(cur ^ 1, ak, wk);
        }
        short8 af[4], bf[4];
        #pragma unroll
        for (int m = 0; m < 4; ++m) af[m] = *(const short8*)(&As[cur][aOff + m * 512]);
        #pragma unroll
        for (int n = 0; n < 4; ++n) bf[n] = *(const short8*)(&Bs[cur][bOff + n * 512]);
        #pragma unroll
        for (int m = 0; m < 4; ++m)
            #pragma unroll
            for (int n = 0; n < 4; ++n)
                acc[m][n] = __builtin_amdgcn_mfma_f32_16x16x32_bf16(af[m], bf[n], acc[m][n], 0, 0, 0);
        __syncthreads();
        cur ^= 1;
    }
#undef STAGE

    int colBase = bn + wn * 64 + (lane & 15);
    int rowBase = bm + wm * 64 + (lane >> 4) * 4;
    const float c0 = 0.7978845608f;
    #pragma unroll
    for (int n = 0; n < 4; ++n) {
        int c = colBase + n * 16;
        float bvv = bias[c];
        #pragma unroll
        for (int m = 0; m < 4; ++m) {
            int r0 = rowBase + m * 16;
            #pragma unroll
            for (int r = 0; r < 4; ++r) {
                float v = acc[m][n][r] + bvv;
                if (act == 1) {
                    // gelu(v) = v * sigmoid(2u) == v*0.5*(1+tanh(u)); __expf form
                    float u = c0 * (v + 0.044715f * v * v * v);
                    v = v / (1.0f + __expf(-2.0f * u));
                }
                size_t row = (size_t)(r0 + r);
                if (omode == 0) {
                    ((float*)outp)[row * N + c] = v;
                } else if (omode == 1) {
                    __hip_bfloat16 h, lo;
                    split2(v, h, lo);
                    ((__hip_bfloat16*)outp)[row * (2 * N) + c]     = h;
                    ((__hip_bfloat16*)outp)[row * (2 * N) + N + c] = lo;
                } else {
                    ((__hip_bfloat16*)outp)[row * N + c] = __float2bfloat16(v);
                }
            }
        }
    }
}

// ---------------- MFMA attention per (b, nh) ----------------------------------------
// qkvP: [M][1152] bf16, HEAD-MAJOR: q at nh*32+d, k at 384+nh*32+d, v at 768+nh*32+d.
__global__ __launch_bounds__(256) void attn_kernel(const __hip_bfloat16* __restrict__ qkvP,
        const int* __restrict__ x, __hip_bfloat16* __restrict__ a2) {
    __shared__ unsigned short qs[112][32];   // Q rows (pad 100-111 garbage: rows discarded)
    __shared__ unsigned short ks[128][32];   // K rows (pad 100-127 garbage: cols masked)
    __shared__ unsigned short vst[32][136];  // V^T [d][kv]; kv 100-127 ZEROED (NaN safety)
    __shared__ unsigned short ps[112][136];  // P bf16 (unnormalized)
    __shared__ int xb[128];
    int t = threadIdx.x;
    int lane = t & 63, wv = t >> 6;
    int b = blockIdx.x / NH_;
    int nh = blockIdx.x % NH_;
    const __hip_bfloat16* base = qkvP + (size_t)b * L_ * QKVN;

    for (int i = t; i < 576; i += 256) {
        int d = i / 18, w = i % 18;
        ((int*)vst)[d * 68 + 50 + w] = 0;
    }
    for (int i = t; i < 128; i += 256) xb[i] = (i < L_) ? x[b * L_ + i] : 0;

    {
        int r16 = lane >> 2, s = lane & 3;
        for (int i = wv; i < 7; i += 4) {
            int row = i * 16 + r16;
            int sp = s ^ (row & 3) ^ ((row >> 2) & 3);
            gload_lds16(base + (size_t)row * QKVN + nh * 32 + sp * 8, &qs[i * 16][0]);
        }
        for (int i = wv; i < 8; i += 4) {
            int row = i * 16 + r16;
            int sp = s ^ (row & 3) ^ ((row >> 2) & 3);
            gload_lds16(base + (size_t)row * QKVN + 384 + nh * 32 + sp * 8, &ks[i * 16][0]);
        }
    }
    if (t < 200) {
        int kv = t >> 1, d0 = (t & 1) * 16;
        const __hip_bfloat16* vsrc = base + (size_t)kv * QKVN + 768 + nh * 32 + d0;
        short8 v0 = *(const short8*)vsrc;
        short8 v1 = *(const short8*)(vsrc + 8);
        #pragma unroll
        for (int j = 0; j < 8; ++j) {
            vst[d0 + j][kv]     = (unsigned short)v0[j];
            vst[d0 + 8 + j][kv] = (unsigned short)v1[j];
        }
    }
    __syncthreads();

    const float scale = 1.0f / sqrtf((float)H_);   // quirky: 1/sqrt(hidden_dim)
    int n = lane & 15, g = lane >> 4;

    for (int rt = wv; rt < 7; rt += 4) {
        int arow = rt * 16 + n;
        int asp = (g ^ (arow & 3) ^ ((arow >> 2) & 3)) * 8;
        short8 aq = *(const short8*)&qs[arow][asp];
        f32x4 s8[8];
        #pragma unroll
        for (int ct = 0; ct < 8; ++ct) {
            int brow = ct * 16 + n;
            int bsp = (g ^ (brow & 3) ^ ((brow >> 2) & 3)) * 8;
            short8 bk = *(const short8*)&ks[brow][bsp];
            f32x4 z = {0.0f, 0.0f, 0.0f, 0.0f};
            s8[ct] = __builtin_amdgcn_mfma_f32_16x16x32_bf16(aq, bk, z, 0, 0, 0);
        }
        #pragma unroll
        for (int ct = 0; ct < 8; ++ct) {
            int col = ct * 16 + n;
            int xv = xb[col];
            #pragma unroll
            for (int r = 0; r < 4; ++r) {
                float v = s8[ct][r] * scale;
                v = (xv == 0) ? -1e10f : v;
                v = (col >= L_) ? -INFINITY : v;
                s8[ct][r] = v;
            }
        }
        float sm[4];
        #pragma unroll
        for (int r = 0; r < 4; ++r) {
            float m = s8[0][r];
            #pragma unroll
            for (int ct = 1; ct < 8; ++ct) m = fmaxf(m, s8[ct][r]);
            m = fmaxf(m, __shfl_xor(m, 1, 16));
            m = fmaxf(m, __shfl_xor(m, 2, 16));
            m = fmaxf(m, __shfl_xor(m, 4, 16));
            m = fmaxf(m, __shfl_xor(m, 8, 16));
            float s = 0.0f;
            #pragma unroll
            for (int ct = 0; ct < 8; ++ct) {
                float p = __expf(s8[ct][r] - m);
                s8[ct][r] = p;
                s += p;
            }
            s += __shfl_xor(s, 1, 16);
            s += __shfl_xor(s, 2, 16);
            s += __shfl_xor(s, 4, 16);
            s += __shfl_xor(s, 8, 16);
            sm[r] = s;
        }
        int prow = rt * 16 + g * 4;
        #pragma unroll
        for (int ct = 0; ct < 8; ++ct) {
            int col = ct * 16 + n;
            #pragma unroll
            for (int r = 0; r < 4; ++r)
                ps[prow + r][col] = f2b(s8[ct][r]);
        }
        f32x4 o0 = {0.0f, 0.0f, 0.0f, 0.0f}, o1 = o0;
        #pragma unroll
        for (int kt = 0; kt < 4; ++kt) {
            short8 pa = *(const short8*)&ps[rt * 16 + n][kt * 32 + g * 8];
            short8 b0 = *(const short8*)&vst[n][kt * 32 + g * 8];
            short8 b1 = *(const short8*)&vst[16 + n][kt * 32 + g * 8];
            o0 = __builtin_amdgcn_mfma_f32_16x16x32_bf16(pa, b0, o0, 0, 0, 0);
            o1 = __builtin_amdgcn_mfma_f32_16x16x32_bf16(pa, b1, o1, 0, 0, 0);
        }
        #pragma unroll
        for (int r = 0; r < 4; ++r) {
            int lrow = prow + r;
            if (lrow < L_) {
                size_t row = (size_t)b * L_ + lrow;
                float inv = 1.0f / sm[r];
                __hip_bfloat16 h, lo;
                float v0 = o0[r] * inv;
                split2(v0, h, lo);
                a2[row * (2 * H_) + nh * DH_ + n]      = h;
                a2[row * (2 * H_) + H_ + nh * DH_ + n] = lo;
                float v1 = o1[r] * inv;
                split2(v1, h, lo);
                a2[row * (2 * H_) + nh * DH_ + 16 + n]      = h;
                a2[row * (2 * H_) + H_ + nh * DH_ + 16 + n] = lo;
            }
        }
    }
}

// ---------------- fused residual + LayerNorm (scalar g,b; ddof=1) * nonpad ---------
template <int MODE>
__global__ __launch_bounds__(128) void ln_kernel(
        const float* __restrict__ Xf,
        const __hip_bfloat16* __restrict__ R2,
        const int* __restrict__ x,
        const float* __restrict__ gp, const float* __restrict__ bp, int layer,
        float* __restrict__ Yf,
        __hip_bfloat16* __restrict__ Y2,
        __hip_bfloat16* __restrict__ acc2) {
    int row = blockIdx.x;
    int tid = threadIdx.x;
    size_t b1 = (size_t)row * H_;
    size_t b2 = (size_t)row * (2 * H_);

    float v[3];
    #pragma unroll
    for (int j = 0; j < 3; ++j) {
        int f = tid + j * 128;
        float r = __bfloat162float(R2[b2 + f]) + __bfloat162float(R2[b2 + H_ + f]);
        v[j] = Xf[b1 + f] + r;
    }

    __shared__ float red[2];
    float s = v[0] + v[1] + v[2];
    #pragma unroll
    for (int off = 32; off > 0; off >>= 1) s += __shfl_down(s, off);
    if ((tid & 63) == 0) red[tid >> 6] = s;
    __syncthreads();
    float mu = (red[0] + red[1]) * (1.0f / 384.0f);
    __syncthreads();

    float d[3];
    float qq = 0.0f;
    #pragma unroll
    for (int j = 0; j < 3; ++j) { d[j] = v[j] - mu; qq += d[j] * d[j]; }
    #pragma unroll
    for (int off = 32; off > 0; off >>= 1) qq += __shfl_down(qq, off);
    if ((tid & 63) == 0) red[tid >> 6] = qq;
    __syncthreads();
    float var = (red[0] + red[1]) * (1.0f / 383.0f);
    float rstd = rsqrtf(var + 1e-8f);

    float g = gp[layer], bb = bp[layer];
    float np_ = (x[row] != 0) ? 1.0f : 0.0f;
    #pragma unroll
    for (int j = 0; j < 3; ++j) {
        int f = tid + j * 128;
        float y = (g * (d[j] * rstd) + bb) * np_;
        if (MODE == 0) {
            __hip_bfloat16 h, lo;
            split2(y, h, lo);
            Y2[b2 + f]      = h;
            Y2[b2 + H_ + f] = lo;
        } else {
            Yf[b1 + f] = y;
            float a = __bfloat162float(acc2[b2 + f]) + __bfloat162float(acc2[b2 + H_ + f]) + y;
            __hip_bfloat16 h, lo;
            split2(a, h, lo);
            acc2[b2 + f]      = h;
            acc2[b2 + H_ + f] = lo;
        }
    }
}

extern "C" void kernel_launch(void* const* d_in, const int* in_sizes, int n_in,
                              void* d_out, int out_size, void* d_ws, size_t ws_size,
                              hipStream_t stream) {
    const int*   x    = (const int*)d_in[0];
    const int*   seg  = (const int*)d_in[1];
    const float* tok  = (const float*)d_in[2];
    const float* sege = (const float*)d_in[3];
    const float* pos  = (const float*)d_in[4];
    const float* Wq   = (const float*)d_in[5];
    const float* bq   = (const float*)d_in[6];
    const float* Wk   = (const float*)d_in[7];
    const float* bk   = (const float*)d_in[8];
    const float* Wv   = (const float*)d_in[9];
    const float* bv   = (const float*)d_in[10];
    const float* Wo   = (const float*)d_in[11];
    const float* bo   = (const float*)d_in[12];
    const float* g1   = (const float*)d_in[13];
    const float* be1  = (const float*)d_in[14];
    const float* W1   = (const float*)d_in[15];
    const float* b1   = (const float*)d_in[16];
    const float* W2   = (const float*)d_in[17];
    const float* b2   = (const float*)d_in[18];
    const float* g2   = (const float*)d_in[19];
    const float* be2  = (const float*)d_in[20];

    char* p = (char*)d_ws;
    __hip_bfloat16* wTL  = (__hip_bfloat16*)p; p += 7077888;
    __hip_bfloat16* acc2 = (__hip_bfloat16*)p; p += 39321600;
    __hip_bfloat16* bE2  = (__hip_bfloat16*)p; p += 39321600;
    float* qkvb          = (float*)p;          p += 27648;
    char* pool           = p;
    __hip_bfloat16* qkvP = (__hip_bfloat16*)pool;                 // [M][1152] bf16 head-major
    __hip_bfloat16* bA2  = (__hip_bfloat16*)(pool + 58982400);    // [M][768] bf16x2
    float*          woF  = (float*)pool;                          // aliases dead qkvP
    __hip_bfloat16* f2   = (__hip_bfloat16*)pool;                 // aliases pool after LN1
    float* out = (float*)d_out;

    const int nch = (ws_size >= 243035136ULL) ? 1 : 2;
    const int MC  = M_ / nch;   // 25600 or 12800, both % 256 == 0

    bias_concat_kernel<<<dim3((NL_ * QKVN + 255) / 256), dim3(256), 0, stream>>>(bq, bk, bv, qkvb);
    embed_kernel<<<dim3((M_ * H_ + 255) / 256), dim3(256), 0, stream>>>(x, seg, tok, sege, pos, acc2);

    for (int l = 0; l < NL_; ++l) {
        // fused per-layer weight prep (single launch)
        transpose_all_kernel<<<dim3(1728), dim3(32, 8), 0, stream>>>(
            Wq + (size_t)l * H_ * H_, Wk + (size_t)l * H_ * H_, Wv + (size_t)l * H_ * H_,
            Wo + (size_t)l * H_ * H_, W1 + (size_t)l * H_ * FF_, W2 + (size_t)l * FF_ * H_, wTL);

        const float* bol = bo + (size_t)l * H_;
        const float* b1l = b1 + (size_t)l * FF_;
        const float* b2l = b2 + (size_t)l * H_;

        // QKV (head-major cols) -> qkvP bf16 : BIG tile, 900 blocks
        gemm_bf16_kernel<0, 1><<<dim3((QKVN / 128) * (M_ / 256)), dim3(512), 0, stream>>>(
            acc2, wTL + OFF_Q, qkvb + (size_t)l * QKVN, qkvP, 2, QKVN, H_, 0, QKVN / 128);
        // MFMA attention -> bA2 bf16x2
        attn_kernel<<<dim3(B_ * NH_), dim3(256), 0, stream>>>(qkvP, x, bA2);
        // Wo -> woF f32 : small-N, keep 128x128 (600 blocks)
        gemm_bf16_kernel<1, 0><<<dim3((H_ / 128) * (M_ / 128)), dim3(256), 0, stream>>>(
            bA2, wTL + OFF_WO, bol, woF, 0, H_, H_, 0, H_ / 128);
        // LN1(woF + acc2) -> bE2
        ln_kernel<0><<<dim3(M_), dim3(128), 0, stream>>>(
            woF, acc2, x, g1, be1, l, nullptr, bE2, nullptr);
        // FFN
        for (int ch = 0; ch < nch; ++ch) {
            gemm_bf16_kernel<2, 1><<<dim3((FF_ / 128) * (MC / 256)), dim3(512), 0, stream>>>(
                bE2 + (size_t)ch * MC * 2 * H_, wTL + OFF_W1, b1l, f2, 1, FF_, H_, 1, FF_ / 128);
            gemm_bf16_kernel<3, 0><<<dim3((H_ / 128) * (MC / 128)), dim3(256), 0, stream>>>(
                f2, wTL + OFF_W2, b2l, out + (size_t)ch * MC * H_, 0, H_, FF_, 0, H_ / 128);
        }
        // LN2(out + bE2) -> out ; acc2 update
        ln_kernel<1><<<dim3(M_), dim3(128), 0, stream>>>(
            out, bE2, x, g2, be2, l, out, nullptr, acc2);
    }
}

// Round 10
// 2545.438 us; speedup vs baseline: 4.2564x; 1.2693x over previous
//
#include <hip/hip_runtime.h>
#include <hip/hip_bf16.h>
#include <math.h>

#define B_  256
#define L_  100
#define H_  384
#define NH_ 12
#define DH_ 32
#define NL_ 6
#define FF_ 1536
#define M_  (B_*L_)   // 25600 rows
#define QKVN 1152     // 3*H

// per-layer transposed bf16x2 weight layout within wTL (elements)
#define OFF_Q  0
#define OFF_K  294912
#define OFF_V  589824
#define OFF_WO 884736
#define OFF_W1 1179648
#define OFF_W2 2359296

typedef __attribute__((ext_vector_type(8))) short short8;
typedef __attribute__((ext_vector_type(4))) float f32x4;

#define GLOBAL_AS __attribute__((address_space(1)))
#define LDS_AS    __attribute__((address_space(3)))

__device__ __forceinline__ void gload_lds16(const void* g, void* l) {
    __builtin_amdgcn_global_load_lds((const GLOBAL_AS void*)g, (LDS_AS void*)l, 16, 0, 0);
}

__device__ __forceinline__ void split2(float v, __hip_bfloat16& hi, __hip_bfloat16& lo) {
    hi = __float2bfloat16(v);
    lo = __float2bfloat16(v - __bfloat162float(hi));
}

__device__ __forceinline__ unsigned short f2b(float v) {
    __hip_bfloat16 h = __float2bfloat16(v);
    return *(unsigned short*)&h;
}

// ---------------- embedding: acc2 = split(tok[x] + seg[s] + pos[l]) * nonpad -------
__global__ void embed_kernel(const int* __restrict__ x, const int* __restrict__ seg,
                             const float* __restrict__ tok, const float* __restrict__ sege,
                             const float* __restrict__ pos,
                             __hip_bfloat16* __restrict__ acc2) {
    int idx = blockIdx.x * blockDim.x + threadIdx.x;
    if (idx >= M_ * H_) return;
    int m = idx / H_;
    int f = idx - m * H_;
    int t = x[m];
    int s = seg[m];
    int l = m % L_;
    float v = tok[t * H_ + f] + sege[s * H_ + f] + pos[l * H_ + f];
    v = (t != 0) ? v : 0.0f;
    __hip_bfloat16 h, lo;
    split2(v, h, lo);
    acc2[(size_t)m * (2 * H_) + f]      = h;
    acc2[(size_t)m * (2 * H_) + H_ + f] = lo;
}

// ------ fused per-layer weight prep: all 6 transposes (f32 -> bf16x2 [N][2K]) ------
// Q/K/V output rows permuted j -> (j%12)*32 + j/12 (head-major).
__global__ void transpose_all_kernel(const float* __restrict__ Wq, const float* __restrict__ Wk,
        const float* __restrict__ Wv, const float* __restrict__ Wo,
        const float* __restrict__ W1, const float* __restrict__ W2,
        __hip_bfloat16* __restrict__ wTL) {
    __shared__ float tile[32][33];
    int bid = blockIdx.x;
    const float* src;
    __hip_bfloat16* dst;
    int K, N, nx, tix, perm = 0;
    if (bid < 432) {               // Q,K,V: 3 x 144 tiles
        int m = bid / 144; tix = bid % 144;
        src = (m == 0) ? Wq : (m == 1 ? Wk : Wv);
        dst = wTL + (m == 0 ? OFF_Q : (m == 1 ? OFF_K : OFF_V));
        K = 384; N = 384; nx = 12; perm = 1;
    } else if (bid < 576) {        // Wo: 144
        tix = bid - 432; src = Wo; dst = wTL + OFF_WO; K = 384; N = 384; nx = 12;
    } else if (bid < 1152) {       // W1: 576
        tix = bid - 576; src = W1; dst = wTL + OFF_W1; K = 384; N = 1536; nx = 48;
    } else {                       // W2: 576
        tix = bid - 1152; src = W2; dst = wTL + OFF_W2; K = 1536; N = 384; nx = 12;
    }
    int n0 = (tix % nx) * 32, k0 = (tix / nx) * 32;
    int tx = threadIdx.x, ty = threadIdx.y;
    #pragma unroll
    for (int i = ty; i < 32; i += 8)
        tile[i][tx] = src[(size_t)(k0 + i) * N + (n0 + tx)];
    __syncthreads();
    #pragma unroll
    for (int i = ty; i < 32; i += 8) {
        float v = tile[tx][i];
        __hip_bfloat16 h, lo;
        split2(v, h, lo);
        int j = n0 + i;
        int jo = perm ? ((j % 12) * 32 + j / 12) : j;
        dst[(size_t)jo * (2 * K) + (k0 + tx)]     = h;
        dst[(size_t)jo * (2 * K) + K + (k0 + tx)] = lo;
    }
}

// bias concat with head-major permutation: out col j' = t*384 + nh*32 + d
__global__ void bias_concat_kernel(const float* __restrict__ bq, const float* __restrict__ bk,
                                   const float* __restrict__ bv, float* __restrict__ out) {
    int i = blockIdx.x * 256 + threadIdx.x;
    if (i >= NL_ * QKVN) return;
    int l = i / QKVN, jp = i - l * QKVN;
    int t = jp / 384, r = jp % 384;
    int h = r >> 5, d = r & 31;
    int j = d * 12 + h;  // original (interleaved) column
    float v = (t == 0) ? bq[l * 384 + j] : (t == 1 ? bk[l * 384 + j] : bv[l * 384 + j]);
    out[i] = v;
}

// -------------------- split-precision MFMA GEMM (templated) ------------------------
// MODEK 0: 3-term C = A_hi@W_hi + A_hi@W_lo + A_lo@W_hi ; A [M][2K], W [N][2K]; Kend=3K
// MODEK 1: 2-term C = (A_hi+A_lo)@W_hi (full-A x bf16-W) ; A [M][2K], W [N][2K]; Kend=2K
// MODEK 2: 2-term C = A@(W_hi+W_lo)  (bf16-A x fp32-W)   ; A [M][K],  W [N][2K]; Kend=2K
// BIG=1: 256x128 tile, 8 waves (512 thr). BIG=0: 128x128, 4 waves (256 thr).
// 2-phase double-buffered pipeline; swizzled LDS (inverse-swizzled gload source +
// swizzled ds_read, rule 21); bijective XCD swizzle. TAG only names the dispatch.
// OMODE: 0 = f32 out [M][N]; 2 = bf16 out [M][N].
template <int TAG, int BIG, int OMODE, int MODEK, int ACT>
__global__ __launch_bounds__(BIG ? 512 : 256) void gemm_bf16_kernel(
        const __hip_bfloat16* __restrict__ A2,
        const __hip_bfloat16* __restrict__ Wt2,
        const float* __restrict__ bias,
        void* __restrict__ outp,
        int N, int K, int nbx) {
    constexpr int BM = BIG ? 256 : 128;
    __shared__ __hip_bfloat16 As[2][BM * 32];
    __shared__ __hip_bfloat16 Bs[2][128 * 32];
    int t = threadIdx.x;
    int lane = t & 63, wv = t >> 6;
    int wm = wv >> 1, wn = wv & 1;

    int nwg = gridDim.x;
    int q8 = nwg >> 3, r8 = nwg & 7;
    int xcd = blockIdx.x & 7, off = blockIdx.x >> 3;
    int swz = (xcd < r8 ? xcd * (q8 + 1) : r8 * (q8 + 1) + (xcd - r8) * q8) + off;
    int bn = (swz % nbx) * 128;
    int bm = (swz / nbx) * BM;

    const int KstA = (MODEK == 2) ? K : 2 * K;   // A storage stride
    const int KstW = 2 * K;                      // W storage stride
    const int Kend = (MODEK == 0) ? 3 * K : 2 * K;
    f32x4 acc[4][4] = {};

    int sr   = t >> 2;
    int sswz = (t & 3) ^ ((t >> 2) & 3) ^ ((t >> 4) & 3);
    const __hip_bfloat16* a_src = A2 + (size_t)(bm + sr) * KstA + sswz * 8;
    const __hip_bfloat16* b_src = Wt2 + (size_t)(bn + sr) * KstW + sswz * 8;

    int slotp = (lane >> 4) ^ (lane & 3) ^ ((lane >> 2) & 3);
    int aOff = (wm * 64 + (lane & 15)) * 32 + slotp * 8;
    int bOff = (wn * 64 + (lane & 15)) * 32 + slotp * 8;

#define STAGE(buf, ak, wk) do { \
        gload_lds16(a_src + (ak), &As[buf][wv * 512]); \
        gload_lds16(a_src + (size_t)(BM / 2) * KstA + (ak), &As[buf][(BM / 2) * 32 + wv * 512]); \
        gload_lds16(b_src + (wk), &Bs[buf][wv * 512]); \
        if (!BIG) gload_lds16(b_src + (size_t)64 * KstW + (wk), &Bs[buf][2048 + wv * 512]); \
    } while (0)

#define KOFFS(k0, ak, wk) do { \
        if (MODEK == 0) { ak = ((k0) < K) ? (k0) : (k0) - K; wk = ((k0) < 2 * K) ? (k0) : (k0) - 2 * K; } \
        else if (MODEK == 1) { ak = (k0); wk = ((k0) < K) ? (k0) : (k0) - K; } \
        else { ak = ((k0) < K) ? (k0) : (k0) - K; wk = (k0); } \
    } while (0)

    int nt = Kend >> 5;
    STAGE(0, 0, 0);
    __syncthreads();
    int cur = 0;
    for (int ti = 0; ti < nt; ++ti) {
        int k1 = (ti + 1) << 5;
        if (ti + 1 < nt) {                        // issue next-tile loads FIRST
            int ak, wk;
            KOFFS(k1, ak, wk);
            STAGE(cur ^ 1, ak, wk);
        }
        short8 af[4], bf[4];
        #pragma unroll
        for (int m = 0; m < 4; ++m) af[m] = *(const short8*)(&As[cur][aOff + m * 512]);
        #pragma unroll
        for (int n = 0; n < 4; ++n) bf[n] = *(const short8*)(&Bs[cur][bOff + n * 512]);
        #pragma unroll
        for (int m = 0; m < 4; ++m)
            #pragma unroll
            for (int n = 0; n < 4; ++n)
                acc[m][n] = __builtin_amdgcn_mfma_f32_16x16x32_bf16(af[m], bf[n], acc[m][n], 0, 0, 0);
        __syncthreads();
        cur ^= 1;
    }
#undef STAGE
#undef KOFFS

    int colBase = bn + wn * 64 + (lane & 15);
    int rowBase = bm + wm * 64 + (lane >> 4) * 4;
    const float c0 = 0.7978845608f;
    #pragma unroll
    for (int n = 0; n < 4; ++n) {
        int c = colBase + n * 16;
        float bvv = bias[c];
        #pragma unroll
        for (int m = 0; m < 4; ++m) {
            int r0 = rowBase + m * 16;
            #pragma unroll
            for (int r = 0; r < 4; ++r) {
                float v = acc[m][n][r] + bvv;
                if (ACT == 1) {
                    // gelu(v) = v*sigmoid(2u) == v*0.5*(1+tanh(u)); __expf form
                    float u = c0 * (v + 0.044715f * v * v * v);
                    v = v / (1.0f + __expf(-2.0f * u));
                }
                size_t row = (size_t)(r0 + r);
                if (OMODE == 0) {
                    ((float*)outp)[row * N + c] = v;
                } else {
                    ((__hip_bfloat16*)outp)[row * N + c] = __float2bfloat16(v);
                }
            }
        }
    }
}

// ---------------- MFMA attention per (b, nh) ----------------------------------------
// qkvP: [M][1152] bf16, HEAD-MAJOR: q at nh*32+d, k at 384+nh*32+d, v at 768+nh*32+d.
__global__ __launch_bounds__(256) void attn_kernel(const __hip_bfloat16* __restrict__ qkvP,
        const int* __restrict__ x, __hip_bfloat16* __restrict__ a2) {
    __shared__ unsigned short qs[112][32];   // Q rows (pad 100-111 garbage: rows discarded)
    __shared__ unsigned short ks[128][32];   // K rows (pad 100-127 garbage: cols masked)
    __shared__ unsigned short vst[32][136];  // V^T [d][kv]; kv 100-127 ZEROED (NaN safety)
    __shared__ unsigned short ps[112][136];  // P bf16 (unnormalized)
    __shared__ int xb[128];
    int t = threadIdx.x;
    int lane = t & 63, wv = t >> 6;
    int b = blockIdx.x / NH_;
    int nh = blockIdx.x % NH_;
    const __hip_bfloat16* base = qkvP + (size_t)b * L_ * QKVN;

    for (int i = t; i < 576; i += 256) {
        int d = i / 18, w = i % 18;
        ((int*)vst)[d * 68 + 50 + w] = 0;
    }
    for (int i = t; i < 128; i += 256) xb[i] = (i < L_) ? x[b * L_ + i] : 0;

    {
        int r16 = lane >> 2, s = lane & 3;
        for (int i = wv; i < 7; i += 4) {
            int row = i * 16 + r16;
            int sp = s ^ (row & 3) ^ ((row >> 2) & 3);
            gload_lds16(base + (size_t)row * QKVN + nh * 32 + sp * 8, &qs[i * 16][0]);
        }
        for (int i = wv; i < 8; i += 4) {
            int row = i * 16 + r16;
            int sp = s ^ (row & 3) ^ ((row >> 2) & 3);
            gload_lds16(base + (size_t)row * QKVN + 384 + nh * 32 + sp * 8, &ks[i * 16][0]);
        }
    }
    if (t < 200) {
        int kv = t >> 1, d0 = (t & 1) * 16;
        const __hip_bfloat16* vsrc = base + (size_t)kv * QKVN + 768 + nh * 32 + d0;
        short8 v0 = *(const short8*)vsrc;
        short8 v1 = *(const short8*)(vsrc + 8);
        #pragma unroll
        for (int j = 0; j < 8; ++j) {
            vst[d0 + j][kv]     = (unsigned short)v0[j];
            vst[d0 + 8 + j][kv] = (unsigned short)v1[j];
        }
    }
    __syncthreads();

    const float scale = 1.0f / sqrtf((float)H_);   // quirky: 1/sqrt(hidden_dim)
    int n = lane & 15, g = lane >> 4;

    for (int rt = wv; rt < 7; rt += 4) {
        int arow = rt * 16 + n;
        int asp = (g ^ (arow & 3) ^ ((arow >> 2) & 3)) * 8;
        short8 aq = *(const short8*)&qs[arow][asp];
        f32x4 s8[8];
        #pragma unroll
        for (int ct = 0; ct < 8; ++ct) {
            int brow = ct * 16 + n;
            int bsp = (g ^ (brow & 3) ^ ((brow >> 2) & 3)) * 8;
            short8 bk = *(const short8*)&ks[brow][bsp];
            f32x4 z = {0.0f, 0.0f, 0.0f, 0.0f};
            s8[ct] = __builtin_amdgcn_mfma_f32_16x16x32_bf16(aq, bk, z, 0, 0, 0);
        }
        #pragma unroll
        for (int ct = 0; ct < 8; ++ct) {
            int col = ct * 16 + n;
            int xv = xb[col];
            #pragma unroll
            for (int r = 0; r < 4; ++r) {
                float v = s8[ct][r] * scale;
                v = (xv == 0) ? -1e10f : v;
                v = (col >= L_) ? -INFINITY : v;
                s8[ct][r] = v;
            }
        }
        float sm[4];
        #pragma unroll
        for (int r = 0; r < 4; ++r) {
            float m = s8[0][r];
            #pragma unroll
            for (int ct = 1; ct < 8; ++ct) m = fmaxf(m, s8[ct][r]);
            m = fmaxf(m, __shfl_xor(m, 1, 16));
            m = fmaxf(m, __shfl_xor(m, 2, 16));
            m = fmaxf(m, __shfl_xor(m, 4, 16));
            m = fmaxf(m, __shfl_xor(m, 8, 16));
            float s = 0.0f;
            #pragma unroll
            for (int ct = 0; ct < 8; ++ct) {
                float p = __expf(s8[ct][r] - m);
                s8[ct][r] = p;
                s += p;
            }
            s += __shfl_xor(s, 1, 16);
            s += __shfl_xor(s, 2, 16);
            s += __shfl_xor(s, 4, 16);
            s += __shfl_xor(s, 8, 16);
            sm[r] = s;
        }
        int prow = rt * 16 + g * 4;
        #pragma unroll
        for (int ct = 0; ct < 8; ++ct) {
            int col = ct * 16 + n;
            #pragma unroll
            for (int r = 0; r < 4; ++r)
                ps[prow + r][col] = f2b(s8[ct][r]);
        }
        f32x4 o0 = {0.0f, 0.0f, 0.0f, 0.0f}, o1 = o0;
        #pragma unroll
        for (int kt = 0; kt < 4; ++kt) {
            short8 pa = *(const short8*)&ps[rt * 16 + n][kt * 32 + g * 8];
            short8 b0 = *(const short8*)&vst[n][kt * 32 + g * 8];
            short8 b1 = *(const short8*)&vst[16 + n][kt * 32 + g * 8];
            o0 = __builtin_amdgcn_mfma_f32_16x16x32_bf16(pa, b0, o0, 0, 0, 0);
            o1 = __builtin_amdgcn_mfma_f32_16x16x32_bf16(pa, b1, o1, 0, 0, 0);
        }
        #pragma unroll
        for (int r = 0; r < 4; ++r) {
            int lrow = prow + r;
            if (lrow < L_) {
                size_t row = (size_t)b * L_ + lrow;
                float inv = 1.0f / sm[r];
                __hip_bfloat16 h, lo;
                float v0 = o0[r] * inv;
                split2(v0, h, lo);
                a2[row * (2 * H_) + nh * DH_ + n]      = h;
                a2[row * (2 * H_) + H_ + nh * DH_ + n] = lo;
                float v1 = o1[r] * inv;
                split2(v1, h, lo);
                a2[row * (2 * H_) + nh * DH_ + 16 + n]      = h;
                a2[row * (2 * H_) + H_ + nh * DH_ + 16 + n] = lo;
            }
        }
    }
}

// ---------------- fused residual + LayerNorm (scalar g,b; ddof=1) * nonpad ---------
template <int MODE>
__global__ __launch_bounds__(128) void ln_kernel(
        const float* __restrict__ Xf,
        const __hip_bfloat16* __restrict__ R2,
        const int* __restrict__ x,
        const float* __restrict__ gp, const float* __restrict__ bp, int layer,
        float* __restrict__ Yf,
        __hip_bfloat16* __restrict__ Y2,
        __hip_bfloat16* __restrict__ acc2) {
    int row = blockIdx.x;
    int tid = threadIdx.x;
    size_t b1 = (size_t)row * H_;
    size_t b2 = (size_t)row * (2 * H_);

    float v[3];
    #pragma unroll
    for (int j = 0; j < 3; ++j) {
        int f = tid + j * 128;
        float r = __bfloat162float(R2[b2 + f]) + __bfloat162float(R2[b2 + H_ + f]);
        v[j] = Xf[b1 + f] + r;
    }

    __shared__ float red[2];
    float s = v[0] + v[1] + v[2];
    #pragma unroll
    for (int off = 32; off > 0; off >>= 1) s += __shfl_down(s, off);
    if ((tid & 63) == 0) red[tid >> 6] = s;
    __syncthreads();
    float mu = (red[0] + red[1]) * (1.0f / 384.0f);
    __syncthreads();

    float d[3];
    float qq = 0.0f;
    #pragma unroll
    for (int j = 0; j < 3; ++j) { d[j] = v[j] - mu; qq += d[j] * d[j]; }
    #pragma unroll
    for (int off = 32; off > 0; off >>= 1) qq += __shfl_down(qq, off);
    if ((tid & 63) == 0) red[tid >> 6] = qq;
    __syncthreads();
    float var = (red[0] + red[1]) * (1.0f / 383.0f);
    float rstd = rsqrtf(var + 1e-8f);

    float g = gp[layer], bb = bp[layer];
    float np_ = (x[row] != 0) ? 1.0f : 0.0f;
    #pragma unroll
    for (int j = 0; j < 3; ++j) {
        int f = tid + j * 128;
        float y = (g * (d[j] * rstd) + bb) * np_;
        if (MODE == 0) {
            __hip_bfloat16 h, lo;
            split2(y, h, lo);
            Y2[b2 + f]      = h;
            Y2[b2 + H_ + f] = lo;
        } else {
            Yf[b1 + f] = y;
            float a = __bfloat162float(acc2[b2 + f]) + __bfloat162float(acc2[b2 + H_ + f]) + y;
            __hip_bfloat16 h, lo;
            split2(a, h, lo);
            acc2[b2 + f]      = h;
            acc2[b2 + H_ + f] = lo;
        }
    }
}

extern "C" void kernel_launch(void* const* d_in, const int* in_sizes, int n_in,
                              void* d_out, int out_size, void* d_ws, size_t ws_size,
                              hipStream_t stream) {
    const int*   x    = (const int*)d_in[0];
    const int*   seg  = (const int*)d_in[1];
    const float* tok  = (const float*)d_in[2];
    const float* sege = (const float*)d_in[3];
    const float* pos  = (const float*)d_in[4];
    const float* Wq   = (const float*)d_in[5];
    const float* bq   = (const float*)d_in[6];
    const float* Wk   = (const float*)d_in[7];
    const float* bk   = (const float*)d_in[8];
    const float* Wv   = (const float*)d_in[9];
    const float* bv   = (const float*)d_in[10];
    const float* Wo   = (const float*)d_in[11];
    const float* bo   = (const float*)d_in[12];
    const float* g1   = (const float*)d_in[13];
    const float* be1  = (const float*)d_in[14];
    const float* W1   = (const float*)d_in[15];
    const float* b1   = (const float*)d_in[16];
    const float* W2   = (const float*)d_in[17];
    const float* b2   = (const float*)d_in[18];
    const float* g2   = (const float*)d_in[19];
    const float* be2  = (const float*)d_in[20];

    // ---- workspace (~184 MiB total; < proven 191 MiB) ----
    char* p = (char*)d_ws;
    __hip_bfloat16* wTL  = (__hip_bfloat16*)p; p += 7077888;      // per-layer weights bf16x2
    __hip_bfloat16* acc2 = (__hip_bfloat16*)p; p += 39321600;     // [M][768] hi|lo
    __hip_bfloat16* bE2  = (__hip_bfloat16*)p; p += 39321600;     // [M][768] hi|lo
    float* qkvb          = (float*)p;          p += 27648;        // concat qkv bias (all layers)
    char* pool           = p;                                     // 98.3 MB
    __hip_bfloat16* qkvP = (__hip_bfloat16*)pool;                 // [M][1152] bf16 head-major (59.0 MB)
    __hip_bfloat16* bA2  = (__hip_bfloat16*)(pool + 58982400);    // [M][768] bf16x2 (39.3 MB)
    float*          woF  = (float*)pool;                          // [M][384] f32 (aliases dead qkvP)
    __hip_bfloat16* f2   = (__hip_bfloat16*)pool;                 // [M][1536] bf16 (78.6 MB, after LN1)
    float* out = (float*)d_out;

    bias_concat_kernel<<<dim3((NL_ * QKVN + 255) / 256), dim3(256), 0, stream>>>(bq, bk, bv, qkvb);
    embed_kernel<<<dim3((M_ * H_ + 255) / 256), dim3(256), 0, stream>>>(x, seg, tok, sege, pos, acc2);

    for (int l = 0; l < NL_; ++l) {
        // fused per-layer weight prep (single launch)
        transpose_all_kernel<<<dim3(1728), dim3(32, 8), 0, stream>>>(
            Wq + (size_t)l * H_ * H_, Wk + (size_t)l * H_ * H_, Wv + (size_t)l * H_ * H_,
            Wo + (size_t)l * H_ * H_, W1 + (size_t)l * H_ * FF_, W2 + (size_t)l * FF_ * H_, wTL);

        const float* bol = bo + (size_t)l * H_;
        const float* b1l = b1 + (size_t)l * FF_;
        const float* b2l = b2 + (size_t)l * H_;

        // QKV (head-major cols), 3-term -> qkvP bf16 : BIG tile, 900 blocks
        gemm_bf16_kernel<0, 1, 2, 0, 0><<<dim3((QKVN / 128) * (M_ / 256)), dim3(512), 0, stream>>>(
            acc2, wTL + OFF_Q, qkvb + (size_t)l * QKVN, qkvP, QKVN, H_, QKVN / 128);
        // MFMA attention -> bA2 bf16x2
        attn_kernel<<<dim3(B_ * NH_), dim3(256), 0, stream>>>(qkvP, x, bA2);
        // Wo, 3-term -> woF f32 : 128x128 (600 blocks)
        gemm_bf16_kernel<1, 0, 0, 0, 0><<<dim3((H_ / 128) * (M_ / 128)), dim3(256), 0, stream>>>(
            bA2, wTL + OFF_WO, bol, woF, H_, H_, H_ / 128);
        // LN1(woF + acc2) -> bE2
        ln_kernel<0><<<dim3(M_), dim3(128), 0, stream>>>(
            woF, acc2, x, g1, be1, l, nullptr, bE2, nullptr);
        // W1, 3-term + gelu -> f2 PLAIN bf16 : BIG tile, 1200 blocks
        gemm_bf16_kernel<2, 1, 2, 0, 1><<<dim3((FF_ / 128) * (M_ / 256)), dim3(512), 0, stream>>>(
            bE2, wTL + OFF_W1, b1l, f2, FF_, H_, FF_ / 128);
        // W2, 2-term (bf16-A x fp32-grade-W) -> out f32 : 128x128, 600 blocks
        gemm_bf16_kernel<3, 0, 0, 2, 0><<<dim3((H_ / 128) * (M_ / 128)), dim3(256), 0, stream>>>(
            f2, wTL + OFF_W2, b2l, out, H_, FF_, H_ / 128);
        // LN2(out + bE2) -> out ; acc2 update
        ln_kernel<1><<<dim3(M_), dim3(128), 0, stream>>>(
            out, bE2, x, g2, be2, l, out, nullptr, acc2);
    }
}

// Round 11
// 2521.991 us; speedup vs baseline: 4.2960x; 1.0093x over previous
//
#include <hip/hip_runtime.h>
#include <hip/hip_bf16.h>
#include <math.h>

#define B_  256
#define L_  100
#define H_  384
#define NH_ 12
#define DH_ 32
#define NL_ 6
#define FF_ 1536
#define M_  (B_*L_)   // 25600 rows
#define QKVN 1152     // 3*H

// per-layer transposed bf16x2 weight layout within wTL (elements)
#define OFF_Q  0
#define OFF_K  294912
#define OFF_V  589824
#define OFF_WO 884736
#define OFF_W1 1179648
#define OFF_W2 2359296

typedef __attribute__((ext_vector_type(8))) short short8;
typedef __attribute__((ext_vector_type(4))) float f32x4;

#define GLOBAL_AS __attribute__((address_space(1)))
#define LDS_AS    __attribute__((address_space(3)))

__device__ __forceinline__ void gload_lds16(const void* g, void* l) {
    __builtin_amdgcn_global_load_lds((const GLOBAL_AS void*)g, (LDS_AS void*)l, 16, 0, 0);
}

__device__ __forceinline__ void split2(float v, __hip_bfloat16& hi, __hip_bfloat16& lo) {
    hi = __float2bfloat16(v);
    lo = __float2bfloat16(v - __bfloat162float(hi));
}

__device__ __forceinline__ unsigned short f2b(float v) {
    __hip_bfloat16 h = __float2bfloat16(v);
    return *(unsigned short*)&h;
}

#define VMW(N) asm volatile("s_waitcnt vmcnt(" #N ")" ::: "memory")

// ---------------- embedding: acc2 = split(tok[x] + seg[s] + pos[l]) * nonpad -------
__global__ void embed_kernel(const int* __restrict__ x, const int* __restrict__ seg,
                             const float* __restrict__ tok, const float* __restrict__ sege,
                             const float* __restrict__ pos,
                             __hip_bfloat16* __restrict__ acc2) {
    int idx = blockIdx.x * blockDim.x + threadIdx.x;
    if (idx >= M_ * H_) return;
    int m = idx / H_;
    int f = idx - m * H_;
    int t = x[m];
    int s = seg[m];
    int l = m % L_;
    float v = tok[t * H_ + f] + sege[s * H_ + f] + pos[l * H_ + f];
    v = (t != 0) ? v : 0.0f;
    __hip_bfloat16 h, lo;
    split2(v, h, lo);
    acc2[(size_t)m * (2 * H_) + f]      = h;
    acc2[(size_t)m * (2 * H_) + H_ + f] = lo;
}

// ------ fused per-layer weight prep: all 6 transposes (f32 -> bf16x2 [N][2K]) ------
// Q/K/V output rows permuted j -> (j%12)*32 + j/12 (head-major).
__global__ void transpose_all_kernel(const float* __restrict__ Wq, const float* __restrict__ Wk,
        const float* __restrict__ Wv, const float* __restrict__ Wo,
        const float* __restrict__ W1, const float* __restrict__ W2,
        __hip_bfloat16* __restrict__ wTL) {
    __shared__ float tile[32][33];
    int bid = blockIdx.x;
    const float* src;
    __hip_bfloat16* dst;
    int K, N, nx, tix, perm = 0;
    if (bid < 432) {               // Q,K,V: 3 x 144 tiles
        int m = bid / 144; tix = bid % 144;
        src = (m == 0) ? Wq : (m == 1 ? Wk : Wv);
        dst = wTL + (m == 0 ? OFF_Q : (m == 1 ? OFF_K : OFF_V));
        K = 384; N = 384; nx = 12; perm = 1;
    } else if (bid < 576) {        // Wo: 144
        tix = bid - 432; src = Wo; dst = wTL + OFF_WO; K = 384; N = 384; nx = 12;
    } else if (bid < 1152) {       // W1: 576
        tix = bid - 576; src = W1; dst = wTL + OFF_W1; K = 384; N = 1536; nx = 48;
    } else {                       // W2: 576
        tix = bid - 1152; src = W2; dst = wTL + OFF_W2; K = 1536; N = 384; nx = 12;
    }
    int n0 = (tix % nx) * 32, k0 = (tix / nx) * 32;
    int tx = threadIdx.x, ty = threadIdx.y;
    #pragma unroll
    for (int i = ty; i < 32; i += 8)
        tile[i][tx] = src[(size_t)(k0 + i) * N + (n0 + tx)];
    __syncthreads();
    #pragma unroll
    for (int i = ty; i < 32; i += 8) {
        float v = tile[tx][i];
        __hip_bfloat16 h, lo;
        split2(v, h, lo);
        int j = n0 + i;
        int jo = perm ? ((j % 12) * 32 + j / 12) : j;
        dst[(size_t)jo * (2 * K) + (k0 + tx)]     = h;
        dst[(size_t)jo * (2 * K) + K + (k0 + tx)] = lo;
    }
}

// bias concat with head-major permutation: out col j' = t*384 + nh*32 + d
__global__ void bias_concat_kernel(const float* __restrict__ bq, const float* __restrict__ bk,
                                   const float* __restrict__ bv, float* __restrict__ out) {
    int i = blockIdx.x * 256 + threadIdx.x;
    if (i >= NL_ * QKVN) return;
    int l = i / QKVN, jp = i - l * QKVN;
    int t = jp / 384, r = jp % 384;
    int h = r >> 5, d = r & 31;
    int j = d * 12 + h;  // original (interleaved) column
    float v = (t == 0) ? bq[l * 384 + j] : (t == 1 ? bk[l * 384 + j] : bv[l * 384 + j]);
    out[i] = v;
}

// -------------------- split-precision MFMA GEMM (templated) ------------------------
// MODEK 0: 3-term C = A_hi@W_hi + A_hi@W_lo + A_lo@W_hi ; A [M][2K], W [N][2K]; Kend=3K
// MODEK 2: 2-term C = A@(W_hi+W_lo)  (bf16-A x fp32-W)   ; A [M][K],  W [N][2K]; Kend=2K
// BIG=1: 256x128 tile, 8 waves. BIG=0: 128x128, 4 waves.
// T4 schedule: 3-buffer LDS, 2-deep prefetch, counted vmcnt (never 0 mid-loop),
// raw s_barrier (no __syncthreads vmcnt(0) drain); T5 setprio around MFMA cluster.
// OMODE: 0 = f32 out [M][N]; 2 = bf16 out [M][N].
template <int TAG, int BIG, int OMODE, int MODEK, int ACT>
__global__ __launch_bounds__(BIG ? 512 : 256) void gemm_bf16_kernel(
        const __hip_bfloat16* __restrict__ A2,
        const __hip_bfloat16* __restrict__ Wt2,
        const float* __restrict__ bias,
        void* __restrict__ outp,
        int N, int K, int nbx) {
    constexpr int BM = BIG ? 256 : 128;
    __shared__ __hip_bfloat16 As[3][BM * 32];
    __shared__ __hip_bfloat16 Bs[3][128 * 32];
    int t = threadIdx.x;
    int lane = t & 63, wv = t >> 6;
    int wm = wv >> 1, wn = wv & 1;

    int nwg = gridDim.x;
    int q8 = nwg >> 3, r8 = nwg & 7;
    int xcd = blockIdx.x & 7, off = blockIdx.x >> 3;
    int swz = (xcd < r8 ? xcd * (q8 + 1) : r8 * (q8 + 1) + (xcd - r8) * q8) + off;
    int bn = (swz % nbx) * 128;
    int bm = (swz / nbx) * BM;

    const int KstA = (MODEK == 2) ? K : 2 * K;   // A storage stride
    const int KstW = 2 * K;                      // W storage stride
    const int Kend = (MODEK == 0) ? 3 * K : 2 * K;
    f32x4 acc[4][4] = {};

    int sr   = t >> 2;
    int sswz = (t & 3) ^ ((t >> 2) & 3) ^ ((t >> 4) & 3);
    const __hip_bfloat16* a_src = A2 + (size_t)(bm + sr) * KstA + sswz * 8;
    const __hip_bfloat16* b_src = Wt2 + (size_t)(bn + sr) * KstW + sswz * 8;

    int slotp = (lane >> 4) ^ (lane & 3) ^ ((lane >> 2) & 3);
    int aOff = (wm * 64 + (lane & 15)) * 32 + slotp * 8;
    int bOff = (wn * 64 + (lane & 15)) * 32 + slotp * 8;

    // loads per STAGE: BIG = 3 (2 A halves + 1 B), SMALL = 4 (2 A + 2 B)
#define STAGE(buf, ak, wk) do { \
        gload_lds16(a_src + (ak), &As[buf][wv * 512]); \
        gload_lds16(a_src + (size_t)(BM / 2) * KstA + (ak), &As[buf][(BM / 2) * 32 + wv * 512]); \
        gload_lds16(b_src + (wk), &Bs[buf][wv * 512]); \
        if (!BIG) gload_lds16(b_src + (size_t)64 * KstW + (wk), &Bs[buf][2048 + wv * 512]); \
    } while (0)

#define KOFFS(k0, ak, wk) do { \
        if (MODEK == 0) { ak = ((k0) < K) ? (k0) : (k0) - K; wk = ((k0) < 2 * K) ? (k0) : (k0) - 2 * K; } \
        else { ak = ((k0) < K) ? (k0) : (k0) - K; wk = (k0); } \
    } while (0)

    int nt = Kend >> 5;   // >= 36 for all shapes used
    {
        int ak, wk;
        KOFFS(0, ak, wk);
        STAGE(0, ak, wk);
        KOFFS(32, ak, wk);
        STAGE(1, ak, wk);
    }
    int c0 = 0, c1 = 1, c2 = 2;   // compute buf, next buf, stage-target buf
    for (int ti = 0; ti < nt; ++ti) {
        if (ti + 2 < nt) {
            int k2 = (ti + 2) << 5;
            int ak, wk;
            KOFFS(k2, ak, wk);
            STAGE(c2, ak, wk);
            if (BIG) { VMW(6); } else { VMW(8); }   // buf c0's loads done; 2 stages in flight
        } else if (ti + 2 == nt) {
            if (BIG) { VMW(3); } else { VMW(4); }   // buf c0 done; 1 stage in flight
        } else {
            VMW(0);                                  // last step
        }
        __builtin_amdgcn_s_barrier();
        short8 af[4], bf[4];
        #pragma unroll
        for (int m = 0; m < 4; ++m) af[m] = *(const short8*)(&As[c0][aOff + m * 512]);
        #pragma unroll
        for (int n = 0; n < 4; ++n) bf[n] = *(const short8*)(&Bs[c0][bOff + n * 512]);
        __builtin_amdgcn_s_setprio(1);
        #pragma unroll
        for (int m = 0; m < 4; ++m)
            #pragma unroll
            for (int n = 0; n < 4; ++n)
                acc[m][n] = __builtin_amdgcn_mfma_f32_16x16x32_bf16(af[m], bf[n], acc[m][n], 0, 0, 0);
        __builtin_amdgcn_s_setprio(0);
        __builtin_amdgcn_s_barrier();   // readers done before c2-rotation overwrites c0
        int tmp = c0; c0 = c1; c1 = c2; c2 = tmp;
    }
#undef STAGE
#undef KOFFS

    int colBase = bn + wn * 64 + (lane & 15);
    int rowBase = bm + wm * 64 + (lane >> 4) * 4;
    const float c0f = 0.7978845608f;
    #pragma unroll
    for (int n = 0; n < 4; ++n) {
        int c = colBase + n * 16;
        float bvv = bias[c];
        #pragma unroll
        for (int m = 0; m < 4; ++m) {
            int r0 = rowBase + m * 16;
            #pragma unroll
            for (int r = 0; r < 4; ++r) {
                float v = acc[m][n][r] + bvv;
                if (ACT == 1) {
                    // gelu(v) = v*sigmoid(2u) == v*0.5*(1+tanh(u)); __expf form
                    float u = c0f * (v + 0.044715f * v * v * v);
                    v = v / (1.0f + __expf(-2.0f * u));
                }
                size_t row = (size_t)(r0 + r);
                if (OMODE == 0) {
                    ((float*)outp)[row * N + c] = v;
                } else {
                    ((__hip_bfloat16*)outp)[row * N + c] = __float2bfloat16(v);
                }
            }
        }
    }
}

// ---------------- MFMA attention per (b, nh) ----------------------------------------
// qkvP: [M][1152] bf16, HEAD-MAJOR: q at nh*32+d, k at 384+nh*32+d, v at 768+nh*32+d.
__global__ __launch_bounds__(256) void attn_kernel(const __hip_bfloat16* __restrict__ qkvP,
        const int* __restrict__ x, __hip_bfloat16* __restrict__ a2) {
    __shared__ unsigned short qs[112][32];   // Q rows (pad 100-111 garbage: rows discarded)
    __shared__ unsigned short ks[128][32];   // K rows (pad 100-127 garbage: cols masked)
    __shared__ unsigned short vst[32][136];  // V^T [d][kv]; kv 100-127 ZEROED (NaN safety)
    __shared__ unsigned short ps[112][136];  // P bf16 (unnormalized)
    __shared__ int xb[128];
    int t = threadIdx.x;
    int lane = t & 63, wv = t >> 6;
    int b = blockIdx.x / NH_;
    int nh = blockIdx.x % NH_;
    const __hip_bfloat16* base = qkvP + (size_t)b * L_ * QKVN;

    for (int i = t; i < 576; i += 256) {
        int d = i / 18, w = i % 18;
        ((int*)vst)[d * 68 + 50 + w] = 0;
    }
    for (int i = t; i < 128; i += 256) xb[i] = (i < L_) ? x[b * L_ + i] : 0;

    {
        int r16 = lane >> 2, s = lane & 3;
        for (int i = wv; i < 7; i += 4) {
            int row = i * 16 + r16;
            int sp = s ^ (row & 3) ^ ((row >> 2) & 3);
            gload_lds16(base + (size_t)row * QKVN + nh * 32 + sp * 8, &qs[i * 16][0]);
        }
        for (int i = wv; i < 8; i += 4) {
            int row = i * 16 + r16;
            int sp = s ^ (row & 3) ^ ((row >> 2) & 3);
            gload_lds16(base + (size_t)row * QKVN + 384 + nh * 32 + sp * 8, &ks[i * 16][0]);
        }
    }
    if (t < 200) {
        int kv = t >> 1, d0 = (t & 1) * 16;
        const __hip_bfloat16* vsrc = base + (size_t)kv * QKVN + 768 + nh * 32 + d0;
        short8 v0 = *(const short8*)vsrc;
        short8 v1 = *(const short8*)(vsrc + 8);
        #pragma unroll
        for (int j = 0; j < 8; ++j) {
            vst[d0 + j][kv]     = (unsigned short)v0[j];
            vst[d0 + 8 + j][kv] = (unsigned short)v1[j];
        }
    }
    __syncthreads();

    const float scale = 1.0f / sqrtf((float)H_);   // quirky: 1/sqrt(hidden_dim)
    int n = lane & 15, g = lane >> 4;

    for (int rt = wv; rt < 7; rt += 4) {
        int arow = rt * 16 + n;
        int asp = (g ^ (arow & 3) ^ ((arow >> 2) & 3)) * 8;
        short8 aq = *(const short8*)&qs[arow][asp];
        f32x4 s8[8];
        #pragma unroll
        for (int ct = 0; ct < 8; ++ct) {
            int brow = ct * 16 + n;
            int bsp = (g ^ (brow & 3) ^ ((brow >> 2) & 3)) * 8;
            short8 bk = *(const short8*)&ks[brow][bsp];
            f32x4 z = {0.0f, 0.0f, 0.0f, 0.0f};
            s8[ct] = __builtin_amdgcn_mfma_f32_16x16x32_bf16(aq, bk, z, 0, 0, 0);
        }
        #pragma unroll
        for (int ct = 0; ct < 8; ++ct) {
            int col = ct * 16 + n;
            int xv = xb[col];
            #pragma unroll
            for (int r = 0; r < 4; ++r) {
                float v = s8[ct][r] * scale;
                v = (xv == 0) ? -1e10f : v;
                v = (col >= L_) ? -INFINITY : v;
                s8[ct][r] = v;
            }
        }
        float sm[4];
        #pragma unroll
        for (int r = 0; r < 4; ++r) {
            float m = s8[0][r];
            #pragma unroll
            for (int ct = 1; ct < 8; ++ct) m = fmaxf(m, s8[ct][r]);
            m = fmaxf(m, __shfl_xor(m, 1, 16));
            m = fmaxf(m, __shfl_xor(m, 2, 16));
            m = fmaxf(m, __shfl_xor(m, 4, 16));
            m = fmaxf(m, __shfl_xor(m, 8, 16));
            float s = 0.0f;
            #pragma unroll
            for (int ct = 0; ct < 8; ++ct) {
                float p = __expf(s8[ct][r] - m);
                s8[ct][r] = p;
                s += p;
            }
            s += __shfl_xor(s, 1, 16);
            s += __shfl_xor(s, 2, 16);
            s += __shfl_xor(s, 4, 16);
            s += __shfl_xor(s, 8, 16);
            sm[r] = s;
        }
        int prow = rt * 16 + g * 4;
        #pragma unroll
        for (int ct = 0; ct < 8; ++ct) {
            int col = ct * 16 + n;
            #pragma unroll
            for (int r = 0; r < 4; ++r)
                ps[prow + r][col] = f2b(s8[ct][r]);
        }
        f32x4 o0 = {0.0f, 0.0f, 0.0f, 0.0f}, o1 = o0;
        #pragma unroll
        for (int kt = 0; kt < 4; ++kt) {
            short8 pa = *(const short8*)&ps[rt * 16 + n][kt * 32 + g * 8];
            short8 b0 = *(const short8*)&vst[n][kt * 32 + g * 8];
            short8 b1 = *(const short8*)&vst[16 + n][kt * 32 + g * 8];
            o0 = __builtin_amdgcn_mfma_f32_16x16x32_bf16(pa, b0, o0, 0, 0, 0);
            o1 = __builtin_amdgcn_mfma_f32_16x16x32_bf16(pa, b1, o1, 0, 0, 0);
        }
        #pragma unroll
        for (int r = 0; r < 4; ++r) {
            int lrow = prow + r;
            if (lrow < L_) {
                size_t row = (size_t)b * L_ + lrow;
                float inv = 1.0f / sm[r];
                __hip_bfloat16 h, lo;
                float v0 = o0[r] * inv;
                split2(v0, h, lo);
                a2[row * (2 * H_) + nh * DH_ + n]      = h;
                a2[row * (2 * H_) + H_ + nh * DH_ + n] = lo;
                float v1 = o1[r] * inv;
                split2(v1, h, lo);
                a2[row * (2 * H_) + nh * DH_ + 16 + n]      = h;
                a2[row * (2 * H_) + H_ + nh * DH_ + 16 + n] = lo;
            }
        }
    }
}

// ---------------- fused residual + LayerNorm (scalar g,b; ddof=1) * nonpad ---------
template <int MODE>
__global__ __launch_bounds__(128) void ln_kernel(
        const float* __restrict__ Xf,
        const __hip_bfloat16* __restrict__ R2,
        const int* __restrict__ x,
        const float* __restrict__ gp, const float* __restrict__ bp, int layer,
        float* __restrict__ Yf,
        __hip_bfloat16* __restrict__ Y2,
        __hip_bfloat16* __restrict__ acc2) {
    int row = blockIdx.x;
    int tid = threadIdx.x;
    size_t b1 = (size_t)row * H_;
    size_t b2 = (size_t)row * (2 * H_);

    float v[3];
    #pragma unroll
    for (int j = 0; j < 3; ++j) {
        int f = tid + j * 128;
        float r = __bfloat162float(R2[b2 + f]) + __bfloat162float(R2[b2 + H_ + f]);
        v[j] = Xf[b1 + f] + r;
    }

    __shared__ float red[2];
    float s = v[0] + v[1] + v[2];
    #pragma unroll
    for (int off = 32; off > 0; off >>= 1) s += __shfl_down(s, off);
    if ((tid & 63) == 0) red[tid >> 6] = s;
    __syncthreads();
    float mu = (red[0] + red[1]) * (1.0f / 384.0f);
    __syncthreads();

    float d[3];
    float qq = 0.0f;
    #pragma unroll
    for (int j = 0; j < 3; ++j) { d[j] = v[j] - mu; qq += d[j] * d[j]; }
    #pragma unroll
    for (int off = 32; off > 0; off >>= 1) qq += __shfl_down(qq, off);
    if ((tid & 63) == 0) red[tid >> 6] = qq;
    __syncthreads();
    float var = (red[0] + red[1]) * (1.0f / 383.0f);
    float rstd = rsqrtf(var + 1e-8f);

    float g = gp[layer], bb = bp[layer];
    float np_ = (x[row] != 0) ? 1.0f : 0.0f;
    #pragma unroll
    for (int j = 0; j < 3; ++j) {
        int f = tid + j * 128;
        float y = (g * (d[j] * rstd) + bb) * np_;
        if (MODE == 0) {
            __hip_bfloat16 h, lo;
            split2(y, h, lo);
            Y2[b2 + f]      = h;
            Y2[b2 + H_ + f] = lo;
        } else {
            Yf[b1 + f] = y;
            float a = __bfloat162float(acc2[b2 + f]) + __bfloat162float(acc2[b2 + H_ + f]) + y;
            __hip_bfloat16 h, lo;
            split2(a, h, lo);
            acc2[b2 + f]      = h;
            acc2[b2 + H_ + f] = lo;
        }
    }
}

extern "C" void kernel_launch(void* const* d_in, const int* in_sizes, int n_in,
                              void* d_out, int out_size, void* d_ws, size_t ws_size,
                              hipStream_t stream) {
    const int*   x    = (const int*)d_in[0];
    const int*   seg  = (const int*)d_in[1];
    const float* tok  = (const float*)d_in[2];
    const float* sege = (const float*)d_in[3];
    const float* pos  = (const float*)d_in[4];
    const float* Wq   = (const float*)d_in[5];
    const float* bq   = (const float*)d_in[6];
    const float* Wk   = (const float*)d_in[7];
    const float* bk   = (const float*)d_in[8];
    const float* Wv   = (const float*)d_in[9];
    const float* bv   = (const float*)d_in[10];
    const float* Wo   = (const float*)d_in[11];
    const float* bo   = (const float*)d_in[12];
    const float* g1   = (const float*)d_in[13];
    const float* be1  = (const float*)d_in[14];
    const float* W1   = (const float*)d_in[15];
    const float* b1   = (const float*)d_in[16];
    const float* W2   = (const float*)d_in[17];
    const float* b2   = (const float*)d_in[18];
    const float* g2   = (const float*)d_in[19];
    const float* be2  = (const float*)d_in[20];

    // ---- workspace (~184 MiB total; < proven 191 MiB) ----
    char* p = (char*)d_ws;
    __hip_bfloat16* wTL  = (__hip_bfloat16*)p; p += 7077888;      // per-layer weights bf16x2
    __hip_bfloat16* acc2 = (__hip_bfloat16*)p; p += 39321600;     // [M][768] hi|lo
    __hip_bfloat16* bE2  = (__hip_bfloat16*)p; p += 39321600;     // [M][768] hi|lo
    float* qkvb          = (float*)p;          p += 27648;        // concat qkv bias (all layers)
    char* pool           = p;                                     // 98.3 MB
    __hip_bfloat16* qkvP = (__hip_bfloat16*)pool;                 // [M][1152] bf16 head-major (59.0 MB)
    __hip_bfloat16* bA2  = (__hip_bfloat16*)(pool + 58982400);    // [M][768] bf16x2 (39.3 MB)
    float*          woF  = (float*)pool;                          // [M][384] f32 (aliases dead qkvP)
    __hip_bfloat16* f2   = (__hip_bfloat16*)pool;                 // [M][1536] bf16 (78.6 MB, after LN1)
    float* out = (float*)d_out;

    bias_concat_kernel<<<dim3((NL_ * QKVN + 255) / 256), dim3(256), 0, stream>>>(bq, bk, bv, qkvb);
    embed_kernel<<<dim3((M_ * H_ + 255) / 256), dim3(256), 0, stream>>>(x, seg, tok, sege, pos, acc2);

    for (int l = 0; l < NL_; ++l) {
        // fused per-layer weight prep (single launch)
        transpose_all_kernel<<<dim3(1728), dim3(32, 8), 0, stream>>>(
            Wq + (size_t)l * H_ * H_, Wk + (size_t)l * H_ * H_, Wv + (size_t)l * H_ * H_,
            Wo + (size_t)l * H_ * H_, W1 + (size_t)l * H_ * FF_, W2 + (size_t)l * FF_ * H_, wTL);

        const float* bol = bo + (size_t)l * H_;
        const float* b1l = b1 + (size_t)l * FF_;
        const float* b2l = b2 + (size_t)l * H_;

        // QKV (head-major cols), 3-term -> qkvP bf16 : BIG tile, 900 blocks
        gemm_bf16_kernel<0, 1, 2, 0, 0><<<dim3((QKVN / 128) * (M_ / 256)), dim3(512), 0, stream>>>(
            acc2, wTL + OFF_Q, qkvb + (size_t)l * QKVN, qkvP, QKVN, H_, QKVN / 128);
        // MFMA attention -> bA2 bf16x2
        attn_kernel<<<dim3(B_ * NH_), dim3(256), 0, stream>>>(qkvP, x, bA2);
        // Wo, 3-term -> woF f32 : 128x128 (600 blocks)
        gemm_bf16_kernel<1, 0, 0, 0, 0><<<dim3((H_ / 128) * (M_ / 128)), dim3(256), 0, stream>>>(
            bA2, wTL + OFF_WO, bol, woF, H_, H_, H_ / 128);
        // LN1(woF + acc2) -> bE2
        ln_kernel<0><<<dim3(M_), dim3(128), 0, stream>>>(
            woF, acc2, x, g1, be1, l, nullptr, bE2, nullptr);
        // W1, 3-term + gelu -> f2 PLAIN bf16 : BIG tile, 1200 blocks
        gemm_bf16_kernel<2, 1, 2, 0, 1><<<dim3((FF_ / 128) * (M_ / 256)), dim3(512), 0, stream>>>(
            bE2, wTL + OFF_W1, b1l, f2, FF_, H_, FF_ / 128);
        // W2, 2-term (bf16-A x fp32-grade-W) -> out f32 : 128x128, 600 blocks
        gemm_bf16_kernel<3, 0, 0, 2, 0><<<dim3((H_ / 128) * (M_ / 128)), dim3(256), 0, stream>>>(
            f2, wTL + OFF_W2, b2l, out, H_, FF_, H_ / 128);
        // LN2(out + bE2) -> out ; acc2 update
        ln_kernel<1><<<dim3(M_), dim3(128), 0, stream>>>(
            out, bE2, x, g2, be2, l, out, nullptr, acc2);
    }
}